// Round 1
// baseline (615.227 us; speedup 1.0000x reference)
//
#include <hip/hip_runtime.h>
#include <math.h>

#define Bb   48
#define Ww   100
#define Nn   1000
#define EMB  128
#define Hh   8
#define QKVd 16
#define LL   101     // depot + 100 neighbors
#define LOCALK 100
#define SORTN 1024
#define TPB  256

// ---- order-preserving float<->key transform (ascending uint == ascending float)
__device__ __forceinline__ unsigned f2key(float x) {
    unsigned u = __float_as_uint(x);
    return (u & 0x80000000u) ? ~u : (u | 0x80000000u);
}
__device__ __forceinline__ float key2f(unsigned k) {
    unsigned u = (k & 0x80000000u) ? (k & 0x7fffffffu) : ~k;
    return __uint_as_float(u);
}

// ---- setup: a[h][e] = sum_d Wk[e, h*16+d] * q[h*16+d] / sqrt(16);  pe table [101][128]
__global__ void setup_kernel(const float* __restrict__ cur,
                             const float* __restrict__ Wq,
                             const float* __restrict__ Wk,
                             float* __restrict__ ws_a,
                             float* __restrict__ ws_pe) {
    __shared__ float qs[EMB];
    const int tid = threadIdx.x;
    if (tid < EMB) {
        float acc = 0.f;
        for (int e = 0; e < EMB; ++e) acc += cur[e] * Wq[e * EMB + tid];
        qs[tid] = acc;
    }
    __syncthreads();
    for (int i = tid; i < Hh * EMB; i += TPB) {
        int h = i >> 7, e = i & 127;
        float acc = 0.f;
        for (int d = 0; d < QKVd; ++d) acc += Wk[e * EMB + h * QKVd + d] * qs[h * QKVd + d];
        ws_a[i] = acc * 0.25f;   // 1/sqrt(QKV)
    }
    const float kneg = -0.14619587891040738f;  // -ln(10000)/63
    for (int i = tid; i < LL * EMB; i += TPB) {
        int l = i >> 7, c = i & 127;
        int ic = c & 63;
        float inv = expf((float)ic * kneg);
        float v = (float)l * inv;
        ws_pe[i] = (c < 64) ? sinf(v) : cosf(v);
    }
}

__global__ __launch_bounds__(TPB) void main_kernel(
    const float* __restrict__ dist,
    const float* __restrict__ xy,
    const float* __restrict__ ndem,
    const float* __restrict__ ninf,
    const float* __restrict__ init_w,
    const float* __restrict__ init_b,
    const float* __restrict__ Wv,
    const float* __restrict__ Wcw,
    const float* __restrict__ Wcb,
    const float* __restrict__ ws_a,
    const float* __restrict__ ws_pe,
    float* __restrict__ out) {

    const int bw  = blockIdx.x;
    const int tid = threadIdx.x;
    const float* distRow = dist + (size_t)bw * Nn;
    const float* maskRow = ninf + (size_t)bw * Nn;
    float*       outRow  = out  + (size_t)bw * Nn;

    // init_k tile, stride 129 => row-scans across lanes hit distinct banks.
    // First 8 KiB aliased as the sort key buffer (sort finishes before kk is written).
    __shared__ __align__(16) float kk[LL * 129];
    unsigned long long* keys = (unsigned long long*)kk;

    __shared__ int   sel[LL];
    __shared__ float sdv[LL];
    __shared__ float sx[LL], sy[LL], sdem[LL], smk[LL];
    __shared__ float attn[Hh * LL];
    __shared__ float ctx[Hh * EMB];
    __shared__ float out128[EMB];
    __shared__ float mh[EMB];
    __shared__ float red[4];
    __shared__ float normsh;

    // zero our output row (poisoned buffer; many barriers before the scatter)
    for (int i = tid; i < Nn; i += TPB) outRow[i] = 0.f;

    // ---- build sort keys: (orderable(dist_eff) << 32) | index; depot & pad = MAX
    for (int i = tid; i < SORTN; i += TPB) {
        unsigned long long kv = ~0ull;
        if (i >= 1 && i < Nn) {
            float de = distRow[i] - maskRow[i];
            kv = ((unsigned long long)f2key(de) << 32) | (unsigned)i;
        }
        keys[i] = kv;
    }
    __syncthreads();

    // ---- bitonic sort ascending (exactly reproduces lax.top_k order: value, then lower idx)
    for (int k = 2; k <= SORTN; k <<= 1) {
        for (int j = k >> 1; j > 0; j >>= 1) {
            for (int i = tid; i < SORTN; i += TPB) {
                int ixj = i ^ j;
                if (ixj > i) {
                    unsigned long long A = keys[i], Bv = keys[ixj];
                    bool up = ((i & k) == 0);
                    if (up ? (A > Bv) : (A < Bv)) { keys[i] = Bv; keys[ixj] = A; }
                }
            }
            __syncthreads();
        }
    }

    // ---- extract top-100 (ascending dist) + depot at slot 0
    if (tid < LOCALK) {
        unsigned long long kv = keys[tid];
        sel[tid + 1] = (int)(unsigned)(kv & 0xffffffffu);
        sdv[tid + 1] = key2f((unsigned)(kv >> 32));
    }
    if (tid == 0) { sel[0] = 0; sdv[0] = INFINITY; }

    // max of dvals (inf -> 0) for coordinate normalization
    float dv = -INFINITY;
    if (tid < LOCALK) {
        float v = sdv[tid + 1];          // own write, no barrier needed
        dv = isinf(v) ? 0.f : v;
    }
    for (int o = 32; o > 0; o >>= 1) dv = fmaxf(dv, __shfl_xor(dv, o, 64));
    if ((tid & 63) == 0) red[tid >> 6] = dv;
    __syncthreads();
    if (tid == 0) normsh = fmaxf(fmaxf(red[0], red[1]), fmaxf(red[2], red[3]));
    __syncthreads();
    const float nmax = normsh;
    const bool  norm_on = (nmax != 0.f);
    const float nfac = nmax + 1e-6f;

    // ---- gather features
    if (tid < LL) {
        int n = sel[tid];
        bool infm = isinf(sdv[tid]);
        float fx = 0.f, fy = 0.f, fd = 0.f;
        if (!infm) {
            size_t base = (size_t)bw * Nn + n;
            fx = xy[base * 2 + 0];
            fy = xy[base * 2 + 1];
            fd = ndem[base];
        }
        if (norm_on) { fx = fx / nfac; fy = fy / nfac; }
        sx[tid] = fx; sy[tid] = fy; sdem[tid] = fd;
        smk[tid] = maskRow[n];
    }
    __syncthreads();

    // ---- init_k[l][e] = sx*w0 + sy*w1 + sdem*w2 + b + pe  (overwrites key buffer)
    for (int i = tid; i < LL * EMB; i += TPB) {
        int l = i >> 7, e = i & 127;
        float v = sx[l] * init_w[e] + sy[l] * init_w[EMB + e] + sdem[l] * init_w[2 * EMB + e]
                + init_b[e] + ws_pe[i];
        kk[l * 129 + e] = v;
    }
    __syncthreads();

    // ---- scores: s[h][l] = init_k[l] . a_h + mask[l]
    for (int i = tid; i < Hh * LL; i += TPB) {
        int h = i / LL, l = i - h * LL;
        const float* ar = ws_a + h * EMB;
        const float* kr = kk + l * 129;
        float acc = 0.f;
        for (int e = 0; e < EMB; ++e) acc += kr[e] * ar[e];
        attn[i] = acc + smk[l];
    }
    __syncthreads();

    // ---- softmax per head: 8 groups of 32 lanes
    {
        int g = tid >> 5;
        int lane = tid & 31;
        float v0 = attn[g * LL + lane];
        float v1 = attn[g * LL + lane + 32];
        float v2 = attn[g * LL + lane + 64];
        float v3 = (lane + 96 < LL) ? attn[g * LL + lane + 96] : -INFINITY;
        float m = fmaxf(fmaxf(v0, v1), fmaxf(v2, v3));
        for (int o = 16; o > 0; o >>= 1) m = fmaxf(m, __shfl_xor(m, o, 32));
        float e0 = expf(v0 - m), e1 = expf(v1 - m), e2 = expf(v2 - m);
        float e3 = (lane + 96 < LL) ? expf(v3 - m) : 0.f;
        float s = e0 + e1 + e2 + e3;
        for (int o = 16; o > 0; o >>= 1) s += __shfl_xor(s, o, 32);
        float inv = 1.f / s;
        attn[g * LL + lane]      = e0 * inv;
        attn[g * LL + lane + 32] = e1 * inv;
        attn[g * LL + lane + 64] = e2 * inv;
        if (lane + 96 < LL) attn[g * LL + lane + 96] = e3 * inv;
    }
    __syncthreads();

    // ---- ctx[h][e] = sum_l attn[h][l] * init_k[l][e]
    for (int i = tid; i < Hh * EMB; i += TPB) {
        int h = i >> 7, e = i & 127;
        const float* ar = attn + h * LL;
        float acc = 0.f;
        for (int l = 0; l < LL; ++l) acc += ar[l] * kk[l * 129 + e];
        ctx[i] = acc;
    }
    __syncthreads();

    // ---- out[j] = ctx[h] . Wv[:, j],  h = j>>4
    if (tid < EMB) {
        int h = tid >> 4;
        const float* cr = ctx + h * EMB;
        float acc = 0.f;
        for (int e = 0; e < EMB; ++e) acc += cr[e] * Wv[e * EMB + tid];
        out128[tid] = acc;
    }
    __syncthreads();

    // ---- mh[e2] = Wc_b[e2] + out . Wc_w[:, e2]
    if (tid < EMB) {
        float acc = Wcb[tid];
        for (int j = 0; j < EMB; ++j) acc += out128[j] * Wcw[j * EMB + tid];
        mh[tid] = acc;
    }
    __syncthreads();

    // ---- score2[l] = mh . init_k[l] / sqrt(128); scatter into zeroed row
    if (tid < LL) {
        const float* kr = kk + tid * 129;
        float acc = 0.f;
        for (int e = 0; e < EMB; ++e) acc += mh[e] * kr[e];
        outRow[sel[tid]] = acc * 0.08838834764831845f;
    }
}

extern "C" void kernel_launch(void* const* d_in, const int* in_sizes, int n_in,
                              void* d_out, int out_size, void* d_ws, size_t ws_size,
                              hipStream_t stream) {
    // setup_inputs order:
    // 0 theta (unused), 1 dist, 2 xy, 3 norm_demand, 4 ninf_mask,
    // 5 init_w, 6 init_b, 7 cur_token, 8 Wq, 9 Wk, 10 Wv, 11 Wc_w, 12 Wc_b
    const float* dist  = (const float*)d_in[1];
    const float* xy    = (const float*)d_in[2];
    const float* ndem  = (const float*)d_in[3];
    const float* ninf  = (const float*)d_in[4];
    const float* initw = (const float*)d_in[5];
    const float* initb = (const float*)d_in[6];
    const float* cur   = (const float*)d_in[7];
    const float* Wq    = (const float*)d_in[8];
    const float* Wk    = (const float*)d_in[9];
    const float* Wv    = (const float*)d_in[10];
    const float* Wcw   = (const float*)d_in[11];
    const float* Wcb   = (const float*)d_in[12];
    float* out = (float*)d_out;

    float* ws_a  = (float*)d_ws;            // [8][128]
    float* ws_pe = ws_a + Hh * EMB;         // [101][128]

    hipLaunchKernelGGL(setup_kernel, dim3(1), dim3(TPB), 0, stream, cur, Wq, Wk, ws_a, ws_pe);
    hipLaunchKernelGGL(main_kernel, dim3(Bb * Ww), dim3(TPB), 0, stream,
                       dist, xy, ndem, ninf, initw, initb, Wv, Wcw, Wcb, ws_a, ws_pe, out);
}

// Round 2
// 213.808 us; speedup vs baseline: 2.8775x; 2.8775x over previous
//
#include <hip/hip_runtime.h>
#include <hip/hip_fp16.h>
#include <math.h>

#define Bb   48
#define Ww   100
#define Nn   1000
#define EMB  128
#define Hh   8
#define QKVd 16
#define LL   101     // depot + 100 neighbors
#define LOCALK 100
#define SORTN 1024
#define TPB  256
#define KSTR 130     // kk row stride in halves (260 B -> bank step 65%32=1)

// ---- order-preserving float<->key transform (ascending uint == ascending float)
__device__ __forceinline__ unsigned f2key(float x) {
    unsigned u = __float_as_uint(x);
    return (u & 0x80000000u) ? ~u : (u | 0x80000000u);
}
__device__ __forceinline__ float key2f(unsigned k) {
    unsigned u = (k & 0x80000000u) ? (k & 0x7fffffffu) : ~k;
    return __uint_as_float(u);
}

// ---- setup: a[h][e] = (Wk[:,h*16:+16] @ q_h)/4 ; pe table [101][128]
__global__ void setup_kernel(const float* __restrict__ cur,
                             const float* __restrict__ Wq,
                             const float* __restrict__ Wk,
                             float* __restrict__ ws_a,
                             float* __restrict__ ws_pe) {
    __shared__ float qs[EMB];
    const int tid = threadIdx.x;
    if (tid < EMB) {
        float acc = 0.f;
        for (int e = 0; e < EMB; ++e) acc += cur[e] * Wq[e * EMB + tid];
        qs[tid] = acc;
    }
    __syncthreads();
    for (int i = tid; i < Hh * EMB; i += TPB) {
        int h = i >> 7, e = i & 127;
        float acc = 0.f;
        for (int d = 0; d < QKVd; ++d) acc += Wk[e * EMB + h * QKVd + d] * qs[h * QKVd + d];
        ws_a[i] = acc * 0.25f;   // 1/sqrt(QKV)
    }
    const float kneg = -0.14619587891040738f;  // -ln(10000)/63
    for (int i = tid; i < LL * EMB; i += TPB) {
        int l = i >> 7, c = i & 127;
        int ic = c & 63;
        float inv = expf((float)ic * kneg);
        float v = (float)l * inv;
        ws_pe[i] = (c < 64) ? sinf(v) : cosf(v);
    }
}

__global__ __launch_bounds__(TPB, 4) void main_kernel(
    const float* __restrict__ dist,
    const float* __restrict__ xy,
    const float* __restrict__ ndem,
    const float* __restrict__ ninf,
    const float* __restrict__ init_w,
    const float* __restrict__ init_b,
    const float* __restrict__ Wv,
    const float* __restrict__ Wcw,
    const float* __restrict__ Wcb,
    const float* __restrict__ ws_a,
    const float* __restrict__ ws_pe,
    float* __restrict__ out) {

    const int bw  = blockIdx.x;
    const int tid = threadIdx.x;
    const float* distRow = dist + (size_t)bw * Nn;
    const float* maskRow = ninf + (size_t)bw * Nn;
    float*       outRow  = out  + (size_t)bw * Nn;

    // u0: sort keys (8 KB) during phase 1; attn/ctx/out128 during phase 2.
    __shared__ __align__(16) char u0[SORTN * 8];
    unsigned long long* keys = (unsigned long long*)u0;
    float* attn   = (float*)(u0);          // 8*101*4 = 3232 B
    float* ctx    = (float*)(u0 + 3232);   // 8*128*4 = 4096 B
    float* out128 = (float*)(u0 + 7328);   // 128*4   =  512 B

    __shared__ __align__(4) __half kk[LL * KSTR];   // init_k, f16, 26260 B
    __shared__ int   hist[256];
    __shared__ unsigned long long list[128];
    __shared__ int   sel[LL];
    __shared__ float sdv[LL];
    __shared__ float sx[LL], sy[LL], sdem[LL], smk[LL];
    __shared__ float mh[EMB];
    __shared__ int   selSh[3];
    __shared__ int   waveSums[4];
    __shared__ unsigned long long pivotSh;
    __shared__ int   cntSh;
    __shared__ float normsh;

    // zero our output row (poisoned buffer; scatter happens at the very end)
    for (int i = tid; i < Nn; i += TPB) outRow[i] = 0.f;

    // ---- build keys: (orderable(dist_eff) << 32) | index; depot & pad = MAX
    for (int i = tid; i < SORTN; i += TPB) {
        unsigned long long kv = ~0ull;
        if (i >= 1 && i < Nn) {
            float de = distRow[i] - maskRow[i];
            kv = ((unsigned long long)f2key(de) << 32) | (unsigned)i;
        }
        keys[i] = kv;
    }
    __syncthreads();

    // ---- exact radix select: find key of 0-based rank 99 (keys are unique)
    unsigned long long prefix = 0;
    int shift = 56;
    int remRank = 99;
    for (int round = 0; round < 8; ++round) {
        shift = 56 - 8 * round;
        hist[tid] = 0;
        __syncthreads();
        for (int i = tid; i < SORTN; i += TPB) {
            unsigned long long kv = keys[i];
            if (round == 0 || (kv >> (shift + 8)) == (prefix >> (shift + 8))) {
                atomicAdd(&hist[(unsigned)((kv >> shift) & 0xffull)], 1);
            }
        }
        __syncthreads();
        int cnt = hist[tid];
        int v = cnt;
        #pragma unroll
        for (int o = 1; o < 64; o <<= 1) {
            int t = __shfl_up(v, o, 64);
            if ((tid & 63) >= o) v += t;
        }
        if ((tid & 63) == 63) waveSums[tid >> 6] = v;
        __syncthreads();
        int wOff = 0;
        #pragma unroll
        for (int w = 0; w < 3; ++w) if ((tid >> 6) > w) wOff += waveSums[w];
        int excl = v + wOff - cnt;
        if (cnt > 0 && remRank >= excl && remRank < excl + cnt) {
            selSh[0] = tid; selSh[1] = excl; selSh[2] = cnt;
        }
        __syncthreads();
        prefix |= ((unsigned long long)selSh[0]) << shift;
        remRank -= selSh[1];
        if (selSh[2] == 1) break;
    }
    // find the exact pivot key (unique match on the resolved prefix)
    for (int i = tid; i < SORTN; i += TPB) {
        unsigned long long kv = keys[i];
        if ((kv >> shift) == (prefix >> shift)) pivotSh = kv;
    }
    if (tid == 0) cntSh = 0;
    if (tid < 128) list[tid] = ~0ull;
    __syncthreads();
    const unsigned long long pivot = pivotSh;

    // ---- compact the 100 keys <= pivot (unordered)
    for (int i = tid; i < SORTN; i += TPB) {
        unsigned long long kv = keys[i];
        if (kv <= pivot) { int p = atomicAdd(&cntSh, 1); list[p] = kv; }
    }
    __syncthreads();

    // ---- wave 0: bitonic sort 128 elements fully in registers (2 per lane)
    if (tid < 64) {
        const int lane = tid;
        unsigned long long e0 = list[lane];
        unsigned long long e1 = list[lane + 64];
        #pragma unroll
        for (int k = 2; k <= 128; k <<= 1) {
            #pragma unroll
            for (int j = k >> 1; j > 0; j >>= 1) {
                if (j == 64) {
                    // same-lane pair (id0=lane, id1=lane+64); k==128 -> ascending
                    unsigned long long lo = (e0 < e1) ? e0 : e1;
                    unsigned long long hi = (e0 < e1) ? e1 : e0;
                    e0 = lo; e1 = hi;
                } else {
                    bool low = (lane & j) == 0;
                    bool up0 = ((lane & k) == 0);
                    bool up1 = (((lane + 64) & k) == 0);
                    unsigned long long o0 = __shfl_xor(e0, j, 64);
                    unsigned long long o1 = __shfl_xor(e1, j, 64);
                    bool min0 = (up0 == low);
                    bool min1 = (up1 == low);
                    e0 = min0 ? ((e0 < o0) ? e0 : o0) : ((e0 > o0) ? e0 : o0);
                    e1 = min1 ? ((e1 < o1) ? e1 : o1) : ((e1 > o1) ? e1 : o1);
                }
            }
        }
        // ranks: e0 -> lane (0..63), e1 -> lane+64 (64..127); keep first 100
        float v0 = key2f((unsigned)(e0 >> 32));
        sel[lane + 1] = (int)(unsigned)(e0 & 0xffffffffu);
        sdv[lane + 1] = v0;
        float dvm = isinf(v0) ? 0.f : v0;
        if (lane + 64 < LOCALK) {
            float v1 = key2f((unsigned)(e1 >> 32));
            sel[lane + 65] = (int)(unsigned)(e1 & 0xffffffffu);
            sdv[lane + 65] = v1;
            dvm = fmaxf(dvm, isinf(v1) ? 0.f : v1);
        }
        #pragma unroll
        for (int o = 32; o > 0; o >>= 1) dvm = fmaxf(dvm, __shfl_xor(dvm, o, 64));
        if (lane == 0) { sel[0] = 0; sdv[0] = INFINITY; normsh = dvm; }
    }
    __syncthreads();

    const float nmax = normsh;
    const bool  norm_on = (nmax != 0.f);
    const float nfac = nmax + 1e-6f;

    // ---- gather features
    if (tid < LL) {
        int n = sel[tid];
        bool infm = isinf(sdv[tid]);
        float fx = 0.f, fy = 0.f, fd = 0.f;
        if (!infm) {
            size_t base = (size_t)bw * Nn + n;
            fx = xy[base * 2 + 0];
            fy = xy[base * 2 + 1];
            fd = ndem[base];
        }
        if (norm_on) { fx = fx / nfac; fy = fy / nfac; }
        sx[tid] = fx; sy[tid] = fy; sdem[tid] = fd;
        smk[tid] = maskRow[n];
    }
    __syncthreads();

    // ---- init_k[l][e] (f16 in LDS, stride KSTR)
    for (int i = tid; i < LL * EMB; i += TPB) {
        int l = i >> 7, e = i & 127;
        float v = sx[l] * init_w[e] + sy[l] * init_w[EMB + e] + sdem[l] * init_w[2 * EMB + e]
                + init_b[e] + ws_pe[i];
        kk[l * KSTR + e] = __float2half(v);
    }
    __syncthreads();

    // ---- scores: s[h][l] = init_k[l] . a_h + mask[l]   (overwrites key region)
    for (int i = tid; i < Hh * LL; i += TPB) {
        int h = i / LL, l = i - h * LL;
        const float* ar = ws_a + h * EMB;
        const __half2* kr = (const __half2*)(kk + l * KSTR);
        float acc = 0.f;
        #pragma unroll 4
        for (int e2 = 0; e2 < EMB / 2; ++e2) {
            float2 f = __half22float2(kr[e2]);
            acc += f.x * ar[2 * e2] + f.y * ar[2 * e2 + 1];
        }
        attn[i] = acc + smk[l];
    }
    __syncthreads();

    // ---- softmax per head: 8 groups of 32 lanes
    {
        int g = tid >> 5;
        int lane = tid & 31;
        float v0 = attn[g * LL + lane];
        float v1 = attn[g * LL + lane + 32];
        float v2 = attn[g * LL + lane + 64];
        float v3 = (lane + 96 < LL) ? attn[g * LL + lane + 96] : -INFINITY;
        float m = fmaxf(fmaxf(v0, v1), fmaxf(v2, v3));
        #pragma unroll
        for (int o = 16; o > 0; o >>= 1) m = fmaxf(m, __shfl_xor(m, o, 32));
        float e0 = expf(v0 - m), e1 = expf(v1 - m), e2 = expf(v2 - m);
        float e3 = (lane + 96 < LL) ? expf(v3 - m) : 0.f;
        float s = e0 + e1 + e2 + e3;
        #pragma unroll
        for (int o = 16; o > 0; o >>= 1) s += __shfl_xor(s, o, 32);
        float inv = 1.f / s;
        attn[g * LL + lane]      = e0 * inv;
        attn[g * LL + lane + 32] = e1 * inv;
        attn[g * LL + lane + 64] = e2 * inv;
        if (lane + 96 < LL) attn[g * LL + lane + 96] = e3 * inv;
    }
    __syncthreads();

    // ---- ctx[h][e] = sum_l attn[h][l] * init_k[l][e]
    for (int i = tid; i < Hh * EMB; i += TPB) {
        int h = i >> 7, e = i & 127;
        const float* ar = attn + h * LL;
        float acc = 0.f;
        for (int l = 0; l < LL; ++l) acc += ar[l] * __half2float(kk[l * KSTR + e]);
        ctx[i] = acc;
    }
    __syncthreads();

    // ---- out[j] = ctx[h] . Wv[:, j],  h = j>>4
    if (tid < EMB) {
        int h = tid >> 4;
        const float* cr = ctx + h * EMB;
        float acc = 0.f;
        for (int e = 0; e < EMB; ++e) acc += cr[e] * Wv[e * EMB + tid];
        out128[tid] = acc;
    }
    __syncthreads();

    // ---- mh[e2] = Wc_b[e2] + out . Wc_w[:, e2]
    if (tid < EMB) {
        float acc = Wcb[tid];
        for (int j = 0; j < EMB; ++j) acc += out128[j] * Wcw[j * EMB + tid];
        mh[tid] = acc;
    }
    __syncthreads();

    // ---- score2[l] = mh . init_k[l] / sqrt(128); scatter into zeroed row
    if (tid < LL) {
        const __half2* kr = (const __half2*)(kk + tid * KSTR);
        float acc = 0.f;
        #pragma unroll 4
        for (int e2 = 0; e2 < EMB / 2; ++e2) {
            float2 f = __half22float2(kr[e2]);
            acc += f.x * mh[2 * e2] + f.y * mh[2 * e2 + 1];
        }
        outRow[sel[tid]] = acc * 0.08838834764831845f;
    }
}

extern "C" void kernel_launch(void* const* d_in, const int* in_sizes, int n_in,
                              void* d_out, int out_size, void* d_ws, size_t ws_size,
                              hipStream_t stream) {
    // setup_inputs order:
    // 0 theta (unused), 1 dist, 2 xy, 3 norm_demand, 4 ninf_mask,
    // 5 init_w, 6 init_b, 7 cur_token, 8 Wq, 9 Wk, 10 Wv, 11 Wc_w, 12 Wc_b
    const float* dist  = (const float*)d_in[1];
    const float* xy    = (const float*)d_in[2];
    const float* ndem  = (const float*)d_in[3];
    const float* ninf  = (const float*)d_in[4];
    const float* initw = (const float*)d_in[5];
    const float* initb = (const float*)d_in[6];
    const float* cur   = (const float*)d_in[7];
    const float* Wq    = (const float*)d_in[8];
    const float* Wk    = (const float*)d_in[9];
    const float* Wv    = (const float*)d_in[10];
    const float* Wcw   = (const float*)d_in[11];
    const float* Wcb   = (const float*)d_in[12];
    float* out = (float*)d_out;

    float* ws_a  = (float*)d_ws;            // [8][128]
    float* ws_pe = ws_a + Hh * EMB;         // [101][128]

    hipLaunchKernelGGL(setup_kernel, dim3(1), dim3(TPB), 0, stream, cur, Wq, Wk, ws_a, ws_pe);
    hipLaunchKernelGGL(main_kernel, dim3(Bb * Ww), dim3(TPB), 0, stream,
                       dist, xy, ndem, ninf, initw, initb, Wv, Wcw, Wcb, ws_a, ws_pe, out);
}

// Round 3
// 150.022 us; speedup vs baseline: 4.1009x; 1.4252x over previous
//
#include <hip/hip_runtime.h>
#include <math.h>

#define Bb   48
#define Ww   100
#define Nn   1000
#define EMB  128
#define Hh   8
#define QKVd 16
#define LL   101     // depot + 100 neighbors
#define LOCALK 100
#define SORTN 1024
#define TPB  256
#define KSTR 136     // halves per kk row (272 B = 17x16B: 16B-aligned rows, odd 16B stride)

typedef _Float16 half2v __attribute__((ext_vector_type(2)));

// ---- order-preserving float<->key transform (ascending uint == ascending float)
__device__ __forceinline__ unsigned f2key(float x) {
    unsigned u = __float_as_uint(x);
    return (u & 0x80000000u) ? ~u : (u | 0x80000000u);
}
__device__ __forceinline__ float key2f(unsigned k) {
    unsigned u = (k & 0x80000000u) ? (k & 0x7fffffffu) : ~k;
    return __uint_as_float(u);
}

// ---- setup: a[h][e] = (Wk[:,h*16:+16] @ q_h)/4 ; pe table [101][128]
__global__ void setup_kernel(const float* __restrict__ cur,
                             const float* __restrict__ Wq,
                             const float* __restrict__ Wk,
                             float* __restrict__ ws_a,
                             float* __restrict__ ws_pe) {
    __shared__ float qs[EMB];
    const int tid = threadIdx.x;
    if (tid < EMB) {
        float acc = 0.f;
        for (int e = 0; e < EMB; ++e) acc += cur[e] * Wq[e * EMB + tid];
        qs[tid] = acc;
    }
    __syncthreads();
    for (int i = tid; i < Hh * EMB; i += TPB) {
        int h = i >> 7, e = i & 127;
        float acc = 0.f;
        for (int d = 0; d < QKVd; ++d) acc += Wk[e * EMB + h * QKVd + d] * qs[h * QKVd + d];
        ws_a[i] = acc * 0.25f;   // 1/sqrt(QKV)
    }
    const float kneg = -0.14619587891040738f;  // -ln(10000)/63
    for (int i = tid; i < LL * EMB; i += TPB) {
        int l = i >> 7, c = i & 127;
        int ic = c & 63;
        float inv = expf((float)ic * kneg);
        float v = (float)l * inv;
        ws_pe[i] = (c < 64) ? sinf(v) : cosf(v);
    }
}

__global__ __launch_bounds__(TPB, 4) void main_kernel(
    const float* __restrict__ dist,
    const float* __restrict__ xy,
    const float* __restrict__ ndem,
    const float* __restrict__ ninf,
    const float* __restrict__ init_w,
    const float* __restrict__ init_b,
    const float* __restrict__ Wv,
    const float* __restrict__ Wcw,
    const float* __restrict__ Wcb,
    const float* __restrict__ ws_a,
    const float* __restrict__ ws_pe,
    float* __restrict__ out) {

    const int bw   = blockIdx.x;
    const int tid  = threadIdx.x;
    const int lane = tid & 63;
    const int wid  = tid >> 6;
    const float* distRow = dist + (size_t)bw * Nn;
    const float* maskRow = ninf + (size_t)bw * Nn;
    float*       outRow  = out  + (size_t)bw * Nn;

    // u0: select-phase hist/list; later attn/ctx/out128 (disjoint lifetimes)
    __shared__ __align__(16) char u0[7840];
    int* hist4 = (int*)u0;                                        // [4][256]
    unsigned long long* list = (unsigned long long*)(u0 + 4096);  // [100]
    float* attn   = (float*)u0;                                   // [8][101] = 3232 B
    float* ctx    = (float*)(u0 + 3232);                          // [8][128] = 4096 B
    float* out128 = (float*)(u0 + 7328);                          // [128]    =  512 B

    __shared__ __align__(16) _Float16 kk[LL * KSTR];   // init_k f16, 27472 B
    __shared__ __align__(16) _Float16 a2h[Hh * EMB];   // a in f16, 2048 B
    __shared__ __align__(16) _Float16 mhh[EMB];        // mh in f16, 256 B
    __shared__ int   sel[LL];                          // idx | 0x40000000 inf-flag
    __shared__ float sx[LL], sy[LL], sdem[LL], smk[LL];
    __shared__ int   selSh[3];
    __shared__ int   waveSums[4];
    __shared__ float red[2];
    __shared__ unsigned long long pivotSh;
    __shared__ int   cntSh;

    // zero our output row (poisoned buffer; scatter happens at the very end)
    for (int i = tid; i < Nn; i += TPB) outRow[i] = 0.f;

    // ---- keys in registers: (orderable(dist_eff) << 32) | index; depot & pad = MAX
    unsigned long long rk[4];
    #pragma unroll
    for (int r = 0; r < 4; ++r) {
        int i = tid + 256 * r;
        unsigned long long kv = ~0ull;
        if (i >= 1 && i < Nn) {
            float de = distRow[i] - maskRow[i];
            kv = ((unsigned long long)f2key(de) << 32) | (unsigned)i;
        }
        rk[r] = kv;
    }
    // a2h fill + hist zero
    #pragma unroll
    for (int r = 0; r < 4; ++r) a2h[tid + 256 * r] = (_Float16)ws_a[tid + 256 * r];
    #pragma unroll
    for (int r = 0; r < 4; ++r) hist4[tid + 256 * r] = 0;
    __syncthreads();

    // ---- exact radix select (MSB-first): find key of 0-based rank 99 (keys unique)
    unsigned long long prefix = 0;
    int shift = 56;
    int remRank = 99;
    int* myhist = hist4 + (wid << 8);
    for (int round = 0; round < 8; ++round) {
        shift = 56 - 8 * round;
        #pragma unroll
        for (int r = 0; r < 4; ++r) {
            unsigned long long kv = rk[r];
            if (round == 0 || (kv >> (shift + 8)) == (prefix >> (shift + 8)))
                atomicAdd(&myhist[(unsigned)((kv >> shift) & 0xffull)], 1);
        }
        __syncthreads();
        int cnt = hist4[tid] + hist4[256 + tid] + hist4[512 + tid] + hist4[768 + tid];
        // only this thread reads column tid -> safe to zero for next round
        hist4[tid] = 0; hist4[256 + tid] = 0; hist4[512 + tid] = 0; hist4[768 + tid] = 0;
        int v = cnt;
        #pragma unroll
        for (int o = 1; o < 64; o <<= 1) {
            int t = __shfl_up(v, o, 64);
            if (lane >= o) v += t;
        }
        if (lane == 63) waveSums[wid] = v;
        __syncthreads();
        int wOff = 0;
        if (wid > 0) wOff += waveSums[0];
        if (wid > 1) wOff += waveSums[1];
        if (wid > 2) wOff += waveSums[2];
        int excl = v + wOff - cnt;
        if (cnt > 0 && remRank >= excl && remRank < excl + cnt) {
            selSh[0] = tid; selSh[1] = excl; selSh[2] = cnt;
        }
        __syncthreads();
        prefix |= ((unsigned long long)selSh[0]) << shift;
        remRank -= selSh[1];
        if (selSh[2] == 1) break;
    }

    // ---- pivot key (unique match on resolved prefix)
    #pragma unroll
    for (int r = 0; r < 4; ++r)
        if ((rk[r] >> shift) == (prefix >> shift)) pivotSh = rk[r];
    if (tid == 0) cntSh = 0;
    __syncthreads();
    const unsigned long long pivot = pivotSh;

    // ---- ballot-compact the 100 keys <= pivot (unordered)
    #pragma unroll
    for (int r = 0; r < 4; ++r) {
        bool p = rk[r] <= pivot;
        unsigned long long m = __ballot(p);
        int c = __popcll(m);
        int base = 0;
        if (lane == 0 && c) base = atomicAdd(&cntSh, c);
        base = __shfl(base, 0, 64);
        if (p) list[base + __popcll(m & ((1ull << lane) - 1ull))] = rk[r];
    }
    __syncthreads();

    // ---- parallel rank (replaces serial bitonic) + norm max
    if (tid < 128) {
        float dvm = 0.f;
        if (tid < LOCALK) {
            unsigned long long kv = list[tid];
            int rank = 0;
            for (int j = 0; j < LOCALK; ++j) rank += (list[j] < kv) ? 1 : 0;
            float v = key2f((unsigned)(kv >> 32));
            bool infm = isinf(v);
            sel[rank + 1] = (int)(unsigned)(kv & 0xffffffffu) | (infm ? 0x40000000 : 0);
            dvm = infm ? 0.f : v;
        }
        #pragma unroll
        for (int o = 32; o > 0; o >>= 1) dvm = fmaxf(dvm, __shfl_xor(dvm, o, 64));
        if (lane == 0) red[wid] = dvm;
    }
    if (tid == 0) sel[0] = 0x40000000;   // depot: idx 0, inf-flag set
    __syncthreads();

    const float nmax = fmaxf(red[0], red[1]);
    const bool  norm_on = (nmax != 0.f);
    const float nfac = nmax + 1e-6f;

    // ---- gather features
    if (tid < LL) {
        int s = sel[tid];
        int n = s & 0xffffff;
        bool infm = (s & 0x40000000) != 0;
        float fx = 0.f, fy = 0.f, fd = 0.f;
        if (!infm) {
            size_t base = (size_t)bw * Nn + n;
            fx = xy[2 * base];
            fy = xy[2 * base + 1];
            fd = ndem[base];
        }
        if (norm_on) { fx /= nfac; fy /= nfac; }
        sx[tid] = fx; sy[tid] = fy; sdem[tid] = fd;
        smk[tid] = maskRow[n];
    }
    __syncthreads();

    // ---- init_k[l][e] (f16, stride KSTR)
    for (int i = tid; i < LL * EMB; i += TPB) {
        int l = i >> 7, e = i & 127;
        float v = sx[l] * init_w[e] + sy[l] * init_w[EMB + e] + sdem[l] * init_w[2 * EMB + e]
                + init_b[e] + ws_pe[i];
        kk[l * KSTR + e] = (_Float16)v;
    }
    __syncthreads();

    // ---- scores: s[h][l] = init_k[l] . a_h + mask[l]  (v_dot2_f32_f16, 4 acc chains)
    for (int i = tid; i < Hh * LL; i += TPB) {
        int h = i / LL, l = i - h * LL;
        const half2v* kr = (const half2v*)(kk + l * KSTR);
        const half2v* ar = (const half2v*)(a2h + h * EMB);
        float c0 = 0.f, c1 = 0.f, c2 = 0.f, c3 = 0.f;
        #pragma unroll
        for (int e2 = 0; e2 < 64; e2 += 4) {
            c0 = __builtin_amdgcn_fdot2(kr[e2],     ar[e2],     c0, false);
            c1 = __builtin_amdgcn_fdot2(kr[e2 + 1], ar[e2 + 1], c1, false);
            c2 = __builtin_amdgcn_fdot2(kr[e2 + 2], ar[e2 + 2], c2, false);
            c3 = __builtin_amdgcn_fdot2(kr[e2 + 3], ar[e2 + 3], c3, false);
        }
        attn[i] = (c0 + c1) + (c2 + c3) + smk[l];
    }
    __syncthreads();

    // ---- softmax per head: 8 groups of 32 lanes
    {
        int g = tid >> 5;
        int ln = tid & 31;
        float v0 = attn[g * LL + ln];
        float v1 = attn[g * LL + ln + 32];
        float v2 = attn[g * LL + ln + 64];
        float v3 = (ln + 96 < LL) ? attn[g * LL + ln + 96] : -INFINITY;
        float m = fmaxf(fmaxf(v0, v1), fmaxf(v2, v3));
        #pragma unroll
        for (int o = 16; o > 0; o >>= 1) m = fmaxf(m, __shfl_xor(m, o, 32));
        float e0 = __expf(v0 - m), e1 = __expf(v1 - m), e2 = __expf(v2 - m);
        float e3 = (ln + 96 < LL) ? __expf(v3 - m) : 0.f;
        float s = e0 + e1 + e2 + e3;
        #pragma unroll
        for (int o = 16; o > 0; o >>= 1) s += __shfl_xor(s, o, 32);
        float inv = 1.f / s;
        attn[g * LL + ln]      = e0 * inv;
        attn[g * LL + ln + 32] = e1 * inv;
        attn[g * LL + ln + 64] = e2 * inv;
        if (ln + 96 < LL) attn[g * LL + ln + 96] = e3 * inv;
    }
    __syncthreads();

    // ---- ctx[h][e] = sum_l attn[h][l] * init_k[l][e]
    // wave-uniform h per iteration: broadcast attn reads; half2 row reads conflict-free
    {
        int slot = tid;
        #pragma unroll
        for (int it = 0; it < 2; ++it, slot += 256) {
            int h = slot >> 6, pr = slot & 63;
            const half2v* kc = (const half2v*)kk + pr;   // element (l, 2pr..2pr+1): idx l*68+pr
            const float* arow = attn + h * LL;
            float x0 = 0.f, y0 = 0.f, x1 = 0.f, y1 = 0.f;
            int l = 0;
            #pragma unroll 4
            for (; l + 2 <= LL; l += 2) {
                half2v ka = kc[l * (KSTR / 2)];
                half2v kb = kc[(l + 1) * (KSTR / 2)];
                float aa = arow[l], ab = arow[l + 1];
                x0 += (float)ka.x * aa; y0 += (float)ka.y * aa;
                x1 += (float)kb.x * ab; y1 += (float)kb.y * ab;
            }
            { half2v ka = kc[l * (KSTR / 2)]; float aa = arow[l];
              x0 += (float)ka.x * aa; y0 += (float)ka.y * aa; }
            float2* cp = (float2*)(ctx + h * EMB + 2 * pr);
            *cp = make_float2(x0 + x1, y0 + y1);
        }
    }
    __syncthreads();

    // ---- out[j] = ctx[h] . Wv[:, j],  h = j>>4
    if (tid < EMB) {
        int h = tid >> 4;
        const float* cr = ctx + h * EMB;
        const float* wv = Wv + tid;
        float c0 = 0.f, c1 = 0.f, c2 = 0.f, c3 = 0.f;
        #pragma unroll 8
        for (int e = 0; e < EMB; e += 4) {
            c0 += cr[e]     * wv[(e)     * EMB];
            c1 += cr[e + 1] * wv[(e + 1) * EMB];
            c2 += cr[e + 2] * wv[(e + 2) * EMB];
            c3 += cr[e + 3] * wv[(e + 3) * EMB];
        }
        out128[tid] = (c0 + c1) + (c2 + c3);
    }
    __syncthreads();

    // ---- mh[e2] = Wc_b[e2] + out . Wc_w[:, e2]   (stored f16 for fdot2)
    if (tid < EMB) {
        const float* wc = Wcw + tid;
        float c0 = Wcb[tid], c1 = 0.f, c2 = 0.f, c3 = 0.f;
        #pragma unroll 8
        for (int j = 0; j < EMB; j += 4) {
            c0 += out128[j]     * wc[(j)     * EMB];
            c1 += out128[j + 1] * wc[(j + 1) * EMB];
            c2 += out128[j + 2] * wc[(j + 2) * EMB];
            c3 += out128[j + 3] * wc[(j + 3) * EMB];
        }
        mhh[tid] = (_Float16)((c0 + c1) + (c2 + c3));
    }
    __syncthreads();

    // ---- score2[l] = mh . init_k[l] / sqrt(128); scatter into zeroed row
    if (tid < LL) {
        const half2v* kr = (const half2v*)(kk + tid * KSTR);
        const half2v* mr = (const half2v*)mhh;
        float c0 = 0.f, c1 = 0.f, c2 = 0.f, c3 = 0.f;
        #pragma unroll
        for (int e2 = 0; e2 < 64; e2 += 4) {
            c0 = __builtin_amdgcn_fdot2(kr[e2],     mr[e2],     c0, false);
            c1 = __builtin_amdgcn_fdot2(kr[e2 + 1], mr[e2 + 1], c1, false);
            c2 = __builtin_amdgcn_fdot2(kr[e2 + 2], mr[e2 + 2], c2, false);
            c3 = __builtin_amdgcn_fdot2(kr[e2 + 3], mr[e2 + 3], c3, false);
        }
        outRow[sel[tid] & 0xffffff] = ((c0 + c1) + (c2 + c3)) * 0.08838834764831845f;
    }
}

extern "C" void kernel_launch(void* const* d_in, const int* in_sizes, int n_in,
                              void* d_out, int out_size, void* d_ws, size_t ws_size,
                              hipStream_t stream) {
    // setup_inputs order:
    // 0 theta (unused), 1 dist, 2 xy, 3 norm_demand, 4 ninf_mask,
    // 5 init_w, 6 init_b, 7 cur_token, 8 Wq, 9 Wk, 10 Wv, 11 Wc_w, 12 Wc_b
    const float* dist  = (const float*)d_in[1];
    const float* xy    = (const float*)d_in[2];
    const float* ndem  = (const float*)d_in[3];
    const float* ninf  = (const float*)d_in[4];
    const float* initw = (const float*)d_in[5];
    const float* initb = (const float*)d_in[6];
    const float* cur   = (const float*)d_in[7];
    const float* Wq    = (const float*)d_in[8];
    const float* Wk    = (const float*)d_in[9];
    const float* Wv    = (const float*)d_in[10];
    const float* Wcw   = (const float*)d_in[11];
    const float* Wcb   = (const float*)d_in[12];
    float* out = (float*)d_out;

    float* ws_a  = (float*)d_ws;            // [8][128] f32
    float* ws_pe = ws_a + Hh * EMB;         // [101][128] f32

    hipLaunchKernelGGL(setup_kernel, dim3(1), dim3(TPB), 0, stream, cur, Wq, Wk, ws_a, ws_pe);
    hipLaunchKernelGGL(main_kernel, dim3(Bb * Ww), dim3(TPB), 0, stream,
                       dist, xy, ndem, ninf, initw, initb, Wv, Wcw, Wcb, ws_a, ws_pe, out);
}

// Round 4
// 122.860 us; speedup vs baseline: 5.0076x; 1.2211x over previous
//
#include <hip/hip_runtime.h>
#include <math.h>

#define Bb   48
#define Ww   100
#define Nn   1000
#define EMB  128
#define Hh   8
#define LL   101     // depot + 100 neighbors
#define LOCALK 100
#define TPB  256

typedef _Float16 half2v __attribute__((ext_vector_type(2)));

// ---- workspace layout (float offsets)
#define WS_A    0        // [8][128] a_h = (Wk q_h)/4
#define WS_PE   1024     // [101][128] pos-enc f32
#define WS_AC   13952    // [3][8] A_i[h] then [8] C[h]
#define WS_WVI  13984    // [4][128]  w_i·Wv[:,hd] (i=3 -> b)
#define WS_PV   14496    // [128][104] pe·Wv column table
#define WS_PEA  27808    // [8][101]  pe[l]·a_h
#define WS_WG   28616    // [3][8][128] w_i·G_h
#define WS_BG   31688    // [128]  Σ_h b·G_h + Wcb
#define WS_PEH  31816    // f16 [101][128] pos-enc
#define WS_PEG2 38280    // f16 tiled [101][128][8]: PEGT[hl][e'] at [(hl>>3)][e'][hl&7]
// total 89992 floats = 360 KB

__device__ __forceinline__ unsigned f2key(float x) {
    unsigned u = __float_as_uint(x);
    return (u & 0x80000000u) ? ~u : (u | 0x80000000u);
}
__device__ __forceinline__ float key2f(unsigned k) {
    unsigned u = (k & 0x80000000u) ? (k & 0x7fffffffu) : ~k;
    return __uint_as_float(u);
}

// ---- S1: q, a, A/C (block 0); pe tables + WVi (blocks 1..55)
__global__ void setup1(const float* __restrict__ cur, const float* __restrict__ Wq,
                       const float* __restrict__ Wk, const float* __restrict__ iw,
                       const float* __restrict__ ib, const float* __restrict__ Wv,
                       float* __restrict__ ws) {
    const int t = threadIdx.x, b = blockIdx.x;
    if (b == 0) {
        __shared__ float qs[EMB];
        __shared__ float as_[Hh * EMB];
        if (t < EMB) {
            float acc = 0.f;
            for (int e = 0; e < EMB; ++e) acc += cur[e] * Wq[e * EMB + t];
            qs[t] = acc;
        }
        __syncthreads();
        for (int i = t; i < Hh * EMB; i += TPB) {
            int h = i >> 7, e = i & 127;
            float acc = 0.f;
            for (int d = 0; d < 16; ++d) acc += Wk[e * EMB + h * 16 + d] * qs[h * 16 + d];
            acc *= 0.25f;
            as_[i] = acc; ws[WS_A + i] = acc;
        }
        __syncthreads();
        if (t < 32) {
            int i = t >> 3, h = t & 7;
            const float* src = (i == 0) ? iw : (i == 1) ? iw + EMB : (i == 2) ? iw + 2 * EMB : ib;
            float acc = 0.f;
            for (int e = 0; e < EMB; ++e) acc += src[e] * as_[h * EMB + e];
            ws[WS_AC + t] = acc;
        }
    } else {
        int base = (b - 1) * TPB + t;
        const float kneg = -0.14619587891040738f;  // -ln(10000)/63
        if (base < LL * EMB) {
            int l = base >> 7, c = base & 127, ic = c & 63;
            float inv = expf((float)ic * kneg);
            float v = (float)l * inv;
            float r = (c < 64) ? sinf(v) : cosf(v);
            ws[WS_PE + base] = r;
            ((_Float16*)(ws + WS_PEH))[base] = (_Float16)r;
        } else if (base < LL * EMB + 512) {
            int j = base - LL * EMB;
            int iv = j >> 7, hd = j & 127;
            const float* src = (iv == 0) ? iw : (iv == 1) ? iw + EMB : (iv == 2) ? iw + 2 * EMB : ib;
            float acc = 0.f;
            for (int e = 0; e < EMB; ++e) acc += src[e] * Wv[e * EMB + hd];
            ws[WS_WVI + j] = acc;
        }
    }
}

// ---- S2a: PV[hd][l] = pe[l]·Wv[:,hd];  PEA[h][l] = pe[l]·a_h
__global__ void setup2a(const float* __restrict__ Wv, float* __restrict__ ws) {
    int idx = blockIdx.x * TPB + threadIdx.x;
    if (idx < 128 * LL) {
        int l = idx >> 7, hd = idx & 127;
        const float* pr = ws + WS_PE + l * EMB;
        float acc = 0.f;
        for (int e = 0; e < EMB; ++e) acc += pr[e] * Wv[e * EMB + hd];
        ws[WS_PV + hd * 104 + l] = acc;
    } else if (idx < 128 * LL + Hh * LL) {
        int j = idx - 128 * LL;
        int h = j / LL, l = j - h * LL;
        const float* pr = ws + WS_PE + l * EMB;
        const float* ar = ws + WS_A + h * EMB;
        float acc = 0.f;
        for (int e = 0; e < EMB; ++e) acc += pr[e] * ar[e];
        ws[WS_PEA + j] = acc;
    }
}

// ---- S2b: PEG2 tiled f16 table; WG; BG
__global__ void setup2b(const float* __restrict__ Wcw, const float* __restrict__ Wcb,
                        float* __restrict__ ws) {
    int idx = blockIdx.x * TPB + threadIdx.x;
    if (idx < 808 * 128) {
        int hl = idx >> 7, e = idx & 127;
        int h = hl / LL, l = hl - h * LL;
        float acc = 0.f;
        for (int d = 0; d < 16; ++d)
            acc += ws[WS_PV + (h * 16 + d) * 104 + l] * Wcw[(h * 16 + d) * EMB + e];
        ((_Float16*)(ws + WS_PEG2))[(hl >> 3) * 1024 + e * 8 + (hl & 7)] = (_Float16)acc;
    } else if (idx < 808 * 128 + 3072) {
        int j = idx - 808 * 128;
        int iwg = j >> 10, r = j & 1023, h = r >> 7, e = r & 127;
        float acc = 0.f;
        for (int d = 0; d < 16; ++d)
            acc += ws[WS_WVI + iwg * 128 + h * 16 + d] * Wcw[(h * 16 + d) * EMB + e];
        ws[WS_WG + j] = acc;
    } else if (idx < 808 * 128 + 3072 + 128) {
        int e = idx - (808 * 128 + 3072);
        float acc = Wcb[e];
        for (int hd = 0; hd < 128; ++hd) acc += ws[WS_WVI + 384 + hd] * Wcw[hd * EMB + e];
        ws[WS_BG + e] = acc;
    }
}

__global__ __launch_bounds__(TPB, 6) void main_kernel(
    const float* __restrict__ dist,
    const float* __restrict__ xy,
    const float* __restrict__ ndem,
    const float* __restrict__ ninf,
    const float* __restrict__ iw,
    const float* __restrict__ ib,
    const float* __restrict__ ws,
    float* __restrict__ out) {

    const int bw   = blockIdx.x;
    const int tid  = threadIdx.x;
    const int lane = tid & 63;
    const int wid  = tid >> 6;
    const float* distRow = dist + (size_t)bw * Nn;
    const float* maskRow = ninf + (size_t)bw * Nn;
    float*       outRow  = out  + (size_t)bw * Nn;

    __shared__ int   hist4[4 * 256];
    __shared__ unsigned long long list[104];
    __shared__ int   sel[LL];                 // idx | 0x40000000 inf-flag
    __shared__ float feat3[3 * LL];           // sx | sy | sdem
    __shared__ float smk[LL];
    __shared__ __align__(16) float attnf[Hh * LL];
    __shared__ __align__(16) _Float16 attnh[Hh * LL];   // 808 halves, 16B-mult
    __shared__ float mhf[EMB];
    __shared__ __align__(16) _Float16 mhh[EMB];
    __shared__ float partial[2][EMB];
    __shared__ float cAC[32];
    __shared__ float coef[Hh][3];
    __shared__ float coefM[4];
    __shared__ int   selSh[3];
    __shared__ int   waveSums[4];
    __shared__ float red[2];
    __shared__ unsigned long long pivotSh;
    __shared__ int   cntSh;

    // zero our output row (poisoned buffer; scatter happens at the very end)
    for (int i = tid; i < Nn; i += TPB) outRow[i] = 0.f;

    // ---- keys in registers: (orderable(dist_eff) << 32) | index; depot & pad = MAX
    unsigned long long rk[4];
    #pragma unroll
    for (int r = 0; r < 4; ++r) {
        int i = tid + 256 * r;
        unsigned long long kv = ~0ull;
        if (i >= 1 && i < Nn) {
            float de = distRow[i] - maskRow[i];
            kv = ((unsigned long long)f2key(de) << 32) | (unsigned)i;
        }
        rk[r] = kv;
    }
    #pragma unroll
    for (int r = 0; r < 4; ++r) hist4[tid + 256 * r] = 0;
    __syncthreads();

    // ---- exact radix select (MSB-first): key of 0-based rank 99 (keys unique)
    unsigned long long prefix = 0;
    int shift = 56;
    int remRank = 99;
    int* myhist = hist4 + (wid << 8);
    for (int round = 0; round < 8; ++round) {
        shift = 56 - 8 * round;
        #pragma unroll
        for (int r = 0; r < 4; ++r) {
            unsigned long long kv = rk[r];
            if (round == 0 || (kv >> (shift + 8)) == (prefix >> (shift + 8)))
                atomicAdd(&myhist[(unsigned)((kv >> shift) & 0xffull)], 1);
        }
        __syncthreads();
        int cnt = hist4[tid] + hist4[256 + tid] + hist4[512 + tid] + hist4[768 + tid];
        hist4[tid] = 0; hist4[256 + tid] = 0; hist4[512 + tid] = 0; hist4[768 + tid] = 0;
        int v = cnt;
        #pragma unroll
        for (int o = 1; o < 64; o <<= 1) {
            int t = __shfl_up(v, o, 64);
            if (lane >= o) v += t;
        }
        if (lane == 63) waveSums[wid] = v;
        __syncthreads();
        int wOff = 0;
        if (wid > 0) wOff += waveSums[0];
        if (wid > 1) wOff += waveSums[1];
        if (wid > 2) wOff += waveSums[2];
        int excl = v + wOff - cnt;
        if (cnt > 0 && remRank >= excl && remRank < excl + cnt) {
            selSh[0] = tid; selSh[1] = excl; selSh[2] = cnt;
        }
        __syncthreads();
        prefix |= ((unsigned long long)selSh[0]) << shift;
        remRank -= selSh[1];
        if (selSh[2] == 1) break;
    }
    #pragma unroll
    for (int r = 0; r < 4; ++r)
        if ((rk[r] >> shift) == (prefix >> shift)) pivotSh = rk[r];
    if (tid == 0) cntSh = 0;
    __syncthreads();
    const unsigned long long pivot = pivotSh;

    // ---- ballot-compact the 100 keys <= pivot (unordered)
    #pragma unroll
    for (int r = 0; r < 4; ++r) {
        bool p = rk[r] <= pivot;
        unsigned long long m = __ballot(p);
        int c = __popcll(m);
        int base = 0;
        if (lane == 0 && c) base = atomicAdd(&cntSh, c);
        base = __shfl(base, 0, 64);
        if (p) list[base + __popcll(m & ((1ull << lane) - 1ull))] = rk[r];
    }
    __syncthreads();

    // ---- parallel rank + norm max
    if (tid < 128) {
        float dvm = 0.f;
        if (tid < LOCALK) {
            unsigned long long kv = list[tid];
            int rank = 0;
            for (int j = 0; j < LOCALK; ++j) rank += (list[j] < kv) ? 1 : 0;
            float v = key2f((unsigned)(kv >> 32));
            bool infm = isinf(v);
            sel[rank + 1] = (int)(unsigned)(kv & 0xffffffffu) | (infm ? 0x40000000 : 0);
            dvm = infm ? 0.f : v;
        }
        #pragma unroll
        for (int o = 32; o > 0; o >>= 1) dvm = fmaxf(dvm, __shfl_xor(dvm, o, 64));
        if (lane == 0) red[wid] = dvm;
    }
    if (tid == 0) sel[0] = 0x40000000;
    __syncthreads();

    const float nmax = fmaxf(red[0], red[1]);
    const bool  norm_on = (nmax != 0.f);
    const float nfac = nmax + 1e-6f;

    // ---- gather features (+ load A/C consts into LDS)
    if (tid < LL) {
        int s = sel[tid];
        int n = s & 0xffffff;
        bool infm = (s & 0x40000000) != 0;
        float fx = 0.f, fy = 0.f, fd = 0.f;
        if (!infm) {
            size_t base = (size_t)bw * Nn + n;
            fx = xy[2 * base];
            fy = xy[2 * base + 1];
            fd = ndem[base];
        }
        if (norm_on) { fx /= nfac; fy /= nfac; }
        feat3[tid] = fx; feat3[LL + tid] = fy; feat3[2 * LL + tid] = fd;
        smk[tid] = maskRow[n];
    }
    if (tid >= 224) cAC[tid - 224] = ws[WS_AC + tid - 224];
    __syncthreads();

    // ---- scores via precomputed tables: s[h][l] (f32)
    for (int i = tid; i < Hh * LL; i += TPB) {
        int h = i / LL, l = i - h * LL;
        float s = feat3[l] * cAC[h] + feat3[LL + l] * cAC[8 + h] + feat3[2 * LL + l] * cAC[16 + h]
                + cAC[24 + h] + ws[WS_PEA + i] + smk[l];
        attnf[i] = s;
    }
    __syncthreads();

    // ---- softmax per head (8 groups x 32 lanes); write f32 normalized + f16
    {
        int g = tid >> 5, ln = tid & 31;
        float v0 = attnf[g * LL + ln];
        float v1 = attnf[g * LL + ln + 32];
        float v2 = attnf[g * LL + ln + 64];
        float v3 = (ln + 96 < LL) ? attnf[g * LL + ln + 96] : -INFINITY;
        float m = fmaxf(fmaxf(v0, v1), fmaxf(v2, v3));
        #pragma unroll
        for (int o = 16; o > 0; o >>= 1) m = fmaxf(m, __shfl_xor(m, o, 32));
        float e0 = __expf(v0 - m), e1 = __expf(v1 - m), e2 = __expf(v2 - m);
        float e3 = (ln + 96 < LL) ? __expf(v3 - m) : 0.f;
        float s = e0 + e1 + e2 + e3;
        #pragma unroll
        for (int o = 16; o > 0; o >>= 1) s += __shfl_xor(s, o, 32);
        float inv = 1.f / s;
        e0 *= inv; e1 *= inv; e2 *= inv; e3 *= inv;
        attnf[g * LL + ln]      = e0;  attnh[g * LL + ln]      = (_Float16)e0;
        attnf[g * LL + ln + 32] = e1;  attnh[g * LL + ln + 32] = (_Float16)e1;
        attnf[g * LL + ln + 64] = e2;  attnh[g * LL + ln + 64] = (_Float16)e2;
        if (ln + 96 < LL) { attnf[g * LL + ln + 96] = e3; attnh[g * LL + ln + 96] = (_Float16)e3; }
    }
    __syncthreads();

    // ---- alpha/beta/gamma (t<192) + main matmul mh_part = attn . PEGT (all threads)
    if (tid < 192) {
        int hf = tid >> 3, k = tid & 7;
        int h = hf / 3, f = hf - 3 * h;
        const float* fr = feat3 + f * LL;
        const float* ar = attnf + h * LL;
        float s = 0.f;
        for (int li = k; li < LL; li += 8) s += ar[li] * fr[li];
        s += __shfl_xor(s, 1, 8); s += __shfl_xor(s, 2, 8); s += __shfl_xor(s, 4, 8);
        if (k == 0) coef[h][f] = s;
    }
    {
        int sd = tid >> 7, e = tid & 127;
        const half2v* pp = (const half2v*)(ws + WS_PEG2) + (size_t)(sd * 50) * 512 + (e << 2);
        const half2v* aa = (const half2v*)attnh + sd * 200;
        int nj = 50 + sd;
        float c0 = 0.f, c1 = 0.f, c2 = 0.f, c3 = 0.f;
        for (int j = 0; j < nj; ++j) {
            half2v a0 = aa[4 * j], a1 = aa[4 * j + 1], a2 = aa[4 * j + 2], a3 = aa[4 * j + 3];
            c0 = __builtin_amdgcn_fdot2(pp[(size_t)j * 512 + 0], a0, c0, false);
            c1 = __builtin_amdgcn_fdot2(pp[(size_t)j * 512 + 1], a1, c1, false);
            c2 = __builtin_amdgcn_fdot2(pp[(size_t)j * 512 + 2], a2, c2, false);
            c3 = __builtin_amdgcn_fdot2(pp[(size_t)j * 512 + 3], a3, c3, false);
        }
        partial[sd][e] = (c0 + c1) + (c2 + c3);
    }
    __syncthreads();

    // ---- mh = BG + partials + rank-3 corrections
    if (tid < EMB) {
        float m = ws[WS_BG + tid] + partial[0][tid] + partial[1][tid];
        #pragma unroll
        for (int h = 0; h < Hh; ++h) {
            m += coef[h][0] * ws[WS_WG + (0 * 8 + h) * EMB + tid]
               + coef[h][1] * ws[WS_WG + (1 * 8 + h) * EMB + tid]
               + coef[h][2] * ws[WS_WG + (2 * 8 + h) * EMB + tid];
        }
        mhf[tid] = m; mhh[tid] = (_Float16)m;
    }
    __syncthreads();

    // ---- mhw dots: coefM[g] = mh . {w0,w1,w2,b}
    {
        int g = tid >> 6;
        const float* src = (g == 0) ? iw : (g == 1) ? iw + EMB : (g == 2) ? iw + 2 * EMB : ib;
        float v = mhf[lane] * src[lane] + mhf[lane + 64] * src[lane + 64];
        #pragma unroll
        for (int o = 32; o > 0; o >>= 1) v += __shfl_xor(v, o, 64);
        if (lane == 0) coefM[g] = v;
    }
    __syncthreads();

    // ---- score2[l] = (base + mh.pe[l]) / sqrt(128); scatter
    if (tid < LL) {
        float base = feat3[tid] * coefM[0] + feat3[LL + tid] * coefM[1]
                   + feat3[2 * LL + tid] * coefM[2] + coefM[3];
        const half2v* pr = (const half2v*)(ws + WS_PEH) + tid * 64;
        const half2v* mr = (const half2v*)mhh;
        float c0 = 0.f, c1 = 0.f, c2 = 0.f, c3 = 0.f;
        #pragma unroll
        for (int j = 0; j < 64; j += 4) {
            c0 = __builtin_amdgcn_fdot2(pr[j],     mr[j],     c0, false);
            c1 = __builtin_amdgcn_fdot2(pr[j + 1], mr[j + 1], c1, false);
            c2 = __builtin_amdgcn_fdot2(pr[j + 2], mr[j + 2], c2, false);
            c3 = __builtin_amdgcn_fdot2(pr[j + 3], mr[j + 3], c3, false);
        }
        outRow[sel[tid] & 0xffffff] = (base + (c0 + c1) + (c2 + c3)) * 0.08838834764831845f;
    }
}

extern "C" void kernel_launch(void* const* d_in, const int* in_sizes, int n_in,
                              void* d_out, int out_size, void* d_ws, size_t ws_size,
                              hipStream_t stream) {
    // 0 theta, 1 dist, 2 xy, 3 norm_demand, 4 ninf_mask,
    // 5 init_w, 6 init_b, 7 cur_token, 8 Wq, 9 Wk, 10 Wv, 11 Wc_w, 12 Wc_b
    const float* dist  = (const float*)d_in[1];
    const float* xy    = (const float*)d_in[2];
    const float* ndem  = (const float*)d_in[3];
    const float* ninf  = (const float*)d_in[4];
    const float* initw = (const float*)d_in[5];
    const float* initb = (const float*)d_in[6];
    const float* cur   = (const float*)d_in[7];
    const float* Wq    = (const float*)d_in[8];
    const float* Wk    = (const float*)d_in[9];
    const float* Wv    = (const float*)d_in[10];
    const float* Wcw   = (const float*)d_in[11];
    const float* Wcb   = (const float*)d_in[12];
    float* out = (float*)d_out;
    float* ws  = (float*)d_ws;

    hipLaunchKernelGGL(setup1,  dim3(56),  dim3(TPB), 0, stream, cur, Wq, Wk, initw, initb, Wv, ws);
    hipLaunchKernelGGL(setup2a, dim3(54),  dim3(TPB), 0, stream, Wv, ws);
    hipLaunchKernelGGL(setup2b, dim3(417), dim3(TPB), 0, stream, Wcw, Wcb, ws);
    hipLaunchKernelGGL(main_kernel, dim3(Bb * Ww), dim3(TPB), 0, stream,
                       dist, xy, ndem, ninf, initw, initb, ws, out);
}

// Round 5
// 110.021 us; speedup vs baseline: 5.5919x; 1.1167x over previous
//
#include <hip/hip_runtime.h>
#include <math.h>

#define Bb   48
#define Ww   100
#define Nn   1000
#define EMB  128
#define Hh   8
#define LL   101     // depot + 100 neighbors
#define LOCALK 100
#define TPB  256

typedef _Float16 half2v __attribute__((ext_vector_type(2)));
typedef _Float16 half8v __attribute__((ext_vector_type(8)));

// ---- workspace layout (float offsets)
#define WS_A    0        // [8][128] a_h = (Wk q_h)/4
#define WS_PE   1024     // [101][128] pos-enc f32
#define WS_AC   13952    // [3][8] A_i[h] then [8] C[h]
#define WS_WVI  13984    // [4][128]  w_i·Wv[:,hd] (i=3 -> b)
#define WS_PV   14496    // [128][104] pe·Wv column table
#define WS_PEA  27808    // [8][101]  pe[l]·a_h
#define WS_WG   28616    // [3][8][128] w_i·G_h
#define WS_BG   31688    // [128]  Σ_h b·G_h + Wcb
#define WS_PEH  31816    // f16 [101][128] pos-enc
#define WS_PEG2 38280    // f16 tiled, 102 tiles of [128][8]: PEGT[hl][e] at [(hl>>3)][e][hl&7]
// PEG2 = 816*128 halves = 52224 floats -> total 90504 floats = 362 KB

__device__ __forceinline__ unsigned f2key(float x) {
    unsigned u = __float_as_uint(x);
    return (u & 0x80000000u) ? ~u : (u | 0x80000000u);
}
__device__ __forceinline__ float key2f(unsigned k) {
    unsigned u = (k & 0x80000000u) ? (k & 0x7fffffffu) : ~k;
    return __uint_as_float(u);
}

// ---- S1: q, a, A/C (block 0); pe tables + WVi (blocks 1..55)
__global__ void setup1(const float* __restrict__ cur, const float* __restrict__ Wq,
                       const float* __restrict__ Wk, const float* __restrict__ iw,
                       const float* __restrict__ ib, const float* __restrict__ Wv,
                       float* __restrict__ ws) {
    const int t = threadIdx.x, b = blockIdx.x;
    if (b == 0) {
        __shared__ float qs[EMB];
        __shared__ float as_[Hh * EMB];
        if (t < EMB) {
            float acc = 0.f;
            for (int e = 0; e < EMB; ++e) acc += cur[e] * Wq[e * EMB + t];
            qs[t] = acc;
        }
        __syncthreads();
        for (int i = t; i < Hh * EMB; i += TPB) {
            int h = i >> 7, e = i & 127;
            float acc = 0.f;
            for (int d = 0; d < 16; ++d) acc += Wk[e * EMB + h * 16 + d] * qs[h * 16 + d];
            acc *= 0.25f;
            as_[i] = acc; ws[WS_A + i] = acc;
        }
        __syncthreads();
        if (t < 32) {
            int i = t >> 3, h = t & 7;
            const float* src = (i == 0) ? iw : (i == 1) ? iw + EMB : (i == 2) ? iw + 2 * EMB : ib;
            float acc = 0.f;
            for (int e = 0; e < EMB; ++e) acc += src[e] * as_[h * EMB + e];
            ws[WS_AC + t] = acc;
        }
    } else {
        int base = (b - 1) * TPB + t;
        const float kneg = -0.14619587891040738f;  // -ln(10000)/63
        if (base < LL * EMB) {
            int l = base >> 7, c = base & 127, ic = c & 63;
            float inv = expf((float)ic * kneg);
            float v = (float)l * inv;
            float r = (c < 64) ? sinf(v) : cosf(v);
            ws[WS_PE + base] = r;
            ((_Float16*)(ws + WS_PEH))[base] = (_Float16)r;
        } else if (base < LL * EMB + 512) {
            int j = base - LL * EMB;
            int iv = j >> 7, hd = j & 127;
            const float* src = (iv == 0) ? iw : (iv == 1) ? iw + EMB : (iv == 2) ? iw + 2 * EMB : ib;
            float acc = 0.f;
            for (int e = 0; e < EMB; ++e) acc += src[e] * Wv[e * EMB + hd];
            ws[WS_WVI + j] = acc;
        }
    }
}

// ---- S2a: PV[hd][l] = pe[l]·Wv[:,hd];  PEA[h][l] = pe[l]·a_h
__global__ void setup2a(const float* __restrict__ Wv, float* __restrict__ ws) {
    int idx = blockIdx.x * TPB + threadIdx.x;
    if (idx < 128 * LL) {
        int l = idx >> 7, hd = idx & 127;
        const float* pr = ws + WS_PE + l * EMB;
        float acc = 0.f;
        for (int e = 0; e < EMB; ++e) acc += pr[e] * Wv[e * EMB + hd];
        ws[WS_PV + hd * 104 + l] = acc;
    } else if (idx < 128 * LL + Hh * LL) {
        int j = idx - 128 * LL;
        int h = j / LL, l = j - h * LL;
        const float* pr = ws + WS_PE + l * EMB;
        const float* ar = ws + WS_A + h * EMB;
        float acc = 0.f;
        for (int e = 0; e < EMB; ++e) acc += pr[e] * ar[e];
        ws[WS_PEA + j] = acc;
    }
}

// ---- S2b: PEG2 tiled f16 table (102 tiles, last zero-padded); WG; BG
__global__ void setup2b(const float* __restrict__ Wcw, const float* __restrict__ Wcb,
                        float* __restrict__ ws) {
    int idx = blockIdx.x * TPB + threadIdx.x;
    if (idx < 816 * 128) {
        int hl = idx >> 7, e = idx & 127;
        float acc = 0.f;
        if (hl < 808) {
            int h = hl / LL, l = hl - h * LL;
            for (int d = 0; d < 16; ++d)
                acc += ws[WS_PV + (h * 16 + d) * 104 + l] * Wcw[(h * 16 + d) * EMB + e];
        }
        ((_Float16*)(ws + WS_PEG2))[(hl >> 3) * 1024 + e * 8 + (hl & 7)] = (_Float16)acc;
    } else if (idx < 816 * 128 + 3072) {
        int j = idx - 816 * 128;
        int iwg = j >> 10, r = j & 1023, h = r >> 7, e = r & 127;
        float acc = 0.f;
        for (int d = 0; d < 16; ++d)
            acc += ws[WS_WVI + iwg * 128 + h * 16 + d] * Wcw[(h * 16 + d) * EMB + e];
        ws[WS_WG + j] = acc;
    } else if (idx < 816 * 128 + 3072 + 128) {
        int e = idx - (816 * 128 + 3072);
        float acc = Wcb[e];
        for (int hd = 0; hd < 128; ++hd) acc += ws[WS_WVI + 384 + hd] * Wcw[hd * EMB + e];
        ws[WS_BG + e] = acc;
    }
}

__global__ __launch_bounds__(TPB, 8) void main_kernel(
    const float* __restrict__ dist,
    const float* __restrict__ xy,
    const float* __restrict__ ndem,
    const float* __restrict__ ninf,
    const float* __restrict__ iw,
    const float* __restrict__ ib,
    const float* __restrict__ ws,
    float* __restrict__ out) {

    const int bw   = blockIdx.x;
    const int tid  = threadIdx.x;
    const int lane = tid & 63;
    const int wid  = tid >> 6;
    const float* distRow = dist + (size_t)bw * Nn;
    const float* maskRow = ninf + (size_t)bw * Nn;
    float*       outRow  = out  + (size_t)bw * Nn;

    __shared__ int   hist4[4 * 256];
    __shared__ unsigned long long list[104];
    __shared__ int   sel[LL];                 // idx | 0x40000000 inf-flag
    __shared__ float feat3[3 * LL];           // sx | sy | sdem
    __shared__ float smk[LL];
    __shared__ __align__(16) _Float16 attnh[816];   // f16 attn, zero-padded to 102 tiles
    __shared__ float mhf[EMB];
    __shared__ __align__(16) _Float16 mhh[EMB];
    __shared__ float partial[2][EMB];
    __shared__ float cAC[32];
    __shared__ float coef[Hh][3];
    __shared__ float coefM[4];
    __shared__ int   selSh[3];
    __shared__ int   waveSums[4];
    __shared__ float red[2];
    __shared__ unsigned long long pivotSh;
    __shared__ int   cntSh;

    // zero our output row (poisoned buffer; scatter happens at the very end)
    for (int i = tid; i < Nn; i += TPB) outRow[i] = 0.f;

    // ---- keys in registers: (orderable(dist_eff) << 32) | index; depot & pad = MAX
    unsigned long long rk[4];
    #pragma unroll
    for (int r = 0; r < 4; ++r) {
        int i = tid + 256 * r;
        unsigned long long kv = ~0ull;
        if (i >= 1 && i < Nn) {
            float de = distRow[i] - maskRow[i];
            kv = ((unsigned long long)f2key(de) << 32) | (unsigned)i;
        }
        rk[r] = kv;
    }
    #pragma unroll
    for (int r = 0; r < 4; ++r) hist4[tid + 256 * r] = 0;
    __syncthreads();

    // ---- exact radix select (MSB-first): key of 0-based rank 99 (keys unique)
    unsigned long long prefix = 0;
    int shift = 56;
    int remRank = 99;
    int* myhist = hist4 + (wid << 8);
    for (int round = 0; round < 8; ++round) {
        shift = 56 - 8 * round;
        #pragma unroll
        for (int r = 0; r < 4; ++r) {
            unsigned long long kv = rk[r];
            if (round == 0 || (kv >> (shift + 8)) == (prefix >> (shift + 8)))
                atomicAdd(&myhist[(unsigned)((kv >> shift) & 0xffull)], 1);
        }
        __syncthreads();
        int cnt = hist4[tid] + hist4[256 + tid] + hist4[512 + tid] + hist4[768 + tid];
        hist4[tid] = 0; hist4[256 + tid] = 0; hist4[512 + tid] = 0; hist4[768 + tid] = 0;
        int v = cnt;
        #pragma unroll
        for (int o = 1; o < 64; o <<= 1) {
            int t = __shfl_up(v, o, 64);
            if (lane >= o) v += t;
        }
        if (lane == 63) waveSums[wid] = v;
        __syncthreads();
        int wOff = 0;
        if (wid > 0) wOff += waveSums[0];
        if (wid > 1) wOff += waveSums[1];
        if (wid > 2) wOff += waveSums[2];
        int excl = v + wOff - cnt;
        if (cnt > 0 && remRank >= excl && remRank < excl + cnt) {
            selSh[0] = tid; selSh[1] = excl; selSh[2] = cnt;
        }
        __syncthreads();
        prefix |= ((unsigned long long)selSh[0]) << shift;
        remRank -= selSh[1];
        if (selSh[2] == 1) break;
    }
    #pragma unroll
    for (int r = 0; r < 4; ++r)
        if ((rk[r] >> shift) == (prefix >> shift)) pivotSh = rk[r];
    if (tid == 0) cntSh = 0;
    __syncthreads();
    const unsigned long long pivot = pivotSh;

    // ---- ballot-compact the 100 keys <= pivot (unordered)
    #pragma unroll
    for (int r = 0; r < 4; ++r) {
        bool p = rk[r] <= pivot;
        unsigned long long m = __ballot(p);
        int c = __popcll(m);
        int base = 0;
        if (lane == 0 && c) base = atomicAdd(&cntSh, c);
        base = __shfl(base, 0, 64);
        if (p) list[base + __popcll(m & ((1ull << lane) - 1ull))] = rk[r];
    }
    __syncthreads();

    // ---- parallel rank + norm max
    if (tid < 128) {
        float dvm = 0.f;
        if (tid < LOCALK) {
            unsigned long long kv = list[tid];
            int rank = 0;
            for (int j = 0; j < LOCALK; ++j) rank += (list[j] < kv) ? 1 : 0;
            float v = key2f((unsigned)(kv >> 32));
            bool infm = isinf(v);
            sel[rank + 1] = (int)(unsigned)(kv & 0xffffffffu) | (infm ? 0x40000000 : 0);
            dvm = infm ? 0.f : v;
        }
        #pragma unroll
        for (int o = 32; o > 0; o >>= 1) dvm = fmaxf(dvm, __shfl_xor(dvm, o, 64));
        if (lane == 0) red[wid] = dvm;
    }
    if (tid == 0) sel[0] = 0x40000000;
    __syncthreads();

    const float nmax = fmaxf(red[0], red[1]);
    const bool  norm_on = (nmax != 0.f);
    const float nfac = nmax + 1e-6f;

    // ---- gather features (+ load A/C consts into LDS)
    if (tid < LL) {
        int s = sel[tid];
        int n = s & 0xffffff;
        bool infm = (s & 0x40000000) != 0;
        float fx = 0.f, fy = 0.f, fd = 0.f;
        if (!infm) {
            size_t base = (size_t)bw * Nn + n;
            fx = xy[2 * base];
            fy = xy[2 * base + 1];
            fd = ndem[base];
        }
        if (norm_on) { fx /= nfac; fy /= nfac; }
        feat3[tid] = fx; feat3[LL + tid] = fy; feat3[2 * LL + tid] = fd;
        smk[tid] = maskRow[n];
    }
    if (tid >= 224) cAC[tid - 224] = ws[WS_AC + tid - 224];
    __syncthreads();

    // ---- fused scores + softmax + coef: group g (32 lanes) owns head g
    {
        int g = tid >> 5, ln = tid & 31;
        int l0 = ln, l1 = ln + 32, l2 = ln + 64, l3 = ln + 96;
        bool ok3 = (l3 < LL);
        const float* pea = ws + WS_PEA + g * LL;
        float A0 = cAC[g], A1 = cAC[8 + g], A2 = cAC[16 + g], C = cAC[24 + g];
        float v0 = feat3[l0] * A0 + feat3[LL + l0] * A1 + feat3[2 * LL + l0] * A2 + C + pea[l0] + smk[l0];
        float v1 = feat3[l1] * A0 + feat3[LL + l1] * A1 + feat3[2 * LL + l1] * A2 + C + pea[l1] + smk[l1];
        float v2 = feat3[l2] * A0 + feat3[LL + l2] * A1 + feat3[2 * LL + l2] * A2 + C + pea[l2] + smk[l2];
        float v3 = ok3 ? (feat3[l3] * A0 + feat3[LL + l3] * A1 + feat3[2 * LL + l3] * A2 + C + pea[l3] + smk[l3])
                       : -INFINITY;
        float m = fmaxf(fmaxf(v0, v1), fmaxf(v2, v3));
        #pragma unroll
        for (int o = 16; o > 0; o >>= 1) m = fmaxf(m, __shfl_xor(m, o, 32));
        float e0 = __expf(v0 - m), e1 = __expf(v1 - m), e2 = __expf(v2 - m);
        float e3 = ok3 ? __expf(v3 - m) : 0.f;
        float s = e0 + e1 + e2 + e3;
        #pragma unroll
        for (int o = 16; o > 0; o >>= 1) s += __shfl_xor(s, o, 32);
        float inv = 1.f / s;
        e0 *= inv; e1 *= inv; e2 *= inv; e3 *= inv;
        attnh[g * LL + l0] = (_Float16)e0;
        attnh[g * LL + l1] = (_Float16)e1;
        attnh[g * LL + l2] = (_Float16)e2;
        if (ok3) attnh[g * LL + l3] = (_Float16)e3;
        if (tid < 8) attnh[808 + tid] = (_Float16)0.f;
        // coef[g][f] = sum_l attn[g][l] * feat3[f][l]  (exact f32, attn in regs)
        #pragma unroll
        for (int f = 0; f < 3; ++f) {
            const float* fr = feat3 + f * LL;
            float cs = e0 * fr[l0] + e1 * fr[l1] + e2 * fr[l2] + (ok3 ? e3 * fr[l3] : 0.f);
            #pragma unroll
            for (int o = 16; o > 0; o >>= 1) cs += __shfl_xor(cs, o, 32);
            if (ln == 0) coef[g][f] = cs;
        }
    }
    __syncthreads();

    // ---- main matmul: partial[sd][e] = sum over strand tiles of attn . PEGT
    {
        int sd = tid >> 7, e = tid & 127;
        const half8v* pbase = (const half8v*)(ws + WS_PEG2) + (size_t)(sd * 51) * 128 + e;
        const half8v* aav = (const half8v*)attnh + sd * 51;
        float c0 = 0.f, c1 = 0.f, c2 = 0.f, c3 = 0.f;
        #pragma unroll 2
        for (int j = 0; j < 51; ++j) {
            half8v p = pbase[(size_t)j * 128];
            half8v a = aav[j];
            c0 = __builtin_amdgcn_fdot2(__builtin_shufflevector(p, p, 0, 1),
                                        __builtin_shufflevector(a, a, 0, 1), c0, false);
            c1 = __builtin_amdgcn_fdot2(__builtin_shufflevector(p, p, 2, 3),
                                        __builtin_shufflevector(a, a, 2, 3), c1, false);
            c2 = __builtin_amdgcn_fdot2(__builtin_shufflevector(p, p, 4, 5),
                                        __builtin_shufflevector(a, a, 4, 5), c2, false);
            c3 = __builtin_amdgcn_fdot2(__builtin_shufflevector(p, p, 6, 7),
                                        __builtin_shufflevector(a, a, 6, 7), c3, false);
        }
        partial[sd][e] = (c0 + c1) + (c2 + c3);
    }
    __syncthreads();

    // ---- mh = BG + partials + rank-3 corrections
    if (tid < EMB) {
        float m = ws[WS_BG + tid] + partial[0][tid] + partial[1][tid];
        #pragma unroll
        for (int h = 0; h < Hh; ++h) {
            m += coef[h][0] * ws[WS_WG + (0 * 8 + h) * EMB + tid]
               + coef[h][1] * ws[WS_WG + (1 * 8 + h) * EMB + tid]
               + coef[h][2] * ws[WS_WG + (2 * 8 + h) * EMB + tid];
        }
        mhf[tid] = m; mhh[tid] = (_Float16)m;
    }
    __syncthreads();

    // ---- coefM[g] = mh . {w0,w1,w2,b}
    {
        int g = tid >> 6;
        const float* src = (g == 0) ? iw : (g == 1) ? iw + EMB : (g == 2) ? iw + 2 * EMB : ib;
        float v = mhf[lane] * src[lane] + mhf[lane + 64] * src[lane + 64];
        #pragma unroll
        for (int o = 32; o > 0; o >>= 1) v += __shfl_xor(v, o, 64);
        if (lane == 0) coefM[g] = v;
    }
    __syncthreads();

    // ---- score2[l] = (base + mh.pe[l]) / sqrt(128); scatter
    if (tid < LL) {
        float base = feat3[tid] * coefM[0] + feat3[LL + tid] * coefM[1]
                   + feat3[2 * LL + tid] * coefM[2] + coefM[3];
        const half2v* pr = (const half2v*)(ws + WS_PEH) + tid * 64;
        const half2v* mr = (const half2v*)mhh;
        float c0 = 0.f, c1 = 0.f, c2 = 0.f, c3 = 0.f;
        #pragma unroll
        for (int j = 0; j < 64; j += 4) {
            c0 = __builtin_amdgcn_fdot2(pr[j],     mr[j],     c0, false);
            c1 = __builtin_amdgcn_fdot2(pr[j + 1], mr[j + 1], c1, false);
            c2 = __builtin_amdgcn_fdot2(pr[j + 2], mr[j + 2], c2, false);
            c3 = __builtin_amdgcn_fdot2(pr[j + 3], mr[j + 3], c3, false);
        }
        outRow[sel[tid] & 0xffffff] = (base + (c0 + c1) + (c2 + c3)) * 0.08838834764831845f;
    }
}

extern "C" void kernel_launch(void* const* d_in, const int* in_sizes, int n_in,
                              void* d_out, int out_size, void* d_ws, size_t ws_size,
                              hipStream_t stream) {
    // 0 theta, 1 dist, 2 xy, 3 norm_demand, 4 ninf_mask,
    // 5 init_w, 6 init_b, 7 cur_token, 8 Wq, 9 Wk, 10 Wv, 11 Wc_w, 12 Wc_b
    const float* dist  = (const float*)d_in[1];
    const float* xy    = (const float*)d_in[2];
    const float* ndem  = (const float*)d_in[3];
    const float* ninf  = (const float*)d_in[4];
    const float* initw = (const float*)d_in[5];
    const float* initb = (const float*)d_in[6];
    const float* cur   = (const float*)d_in[7];
    const float* Wq    = (const float*)d_in[8];
    const float* Wk    = (const float*)d_in[9];
    const float* Wv    = (const float*)d_in[10];
    const float* Wcw   = (const float*)d_in[11];
    const float* Wcb   = (const float*)d_in[12];
    float* out = (float*)d_out;
    float* ws  = (float*)d_ws;

    hipLaunchKernelGGL(setup1,  dim3(56),  dim3(TPB), 0, stream, cur, Wq, Wk, initw, initb, Wv, ws);
    hipLaunchKernelGGL(setup2a, dim3(54),  dim3(TPB), 0, stream, Wv, ws);
    hipLaunchKernelGGL(setup2b, dim3(421), dim3(TPB), 0, stream, Wcw, Wcb, ws);
    hipLaunchKernelGGL(main_kernel, dim3(Bb * Ww), dim3(TPB), 0, stream,
                       dist, xy, ndem, ninf, initw, initb, ws, out);
}

// Round 6
// 104.449 us; speedup vs baseline: 5.8902x; 1.0534x over previous
//
#include <hip/hip_runtime.h>
#include <math.h>

#define Bb   48
#define Ww   100
#define Nn   1000
#define EMB  128
#define Hh   8
#define LL   101     // depot + 100 neighbors
#define LOCALK 100
#define TPB  256

typedef _Float16 half2v __attribute__((ext_vector_type(2)));
typedef _Float16 half8v __attribute__((ext_vector_type(8)));

// ---- workspace layout (float offsets)
#define WS_A    0        // [8][128] f32  a_h = (Wk q_h)/4
#define WS_PE   1024     // [101][128] f32 pos-enc
#define WS_AC   13952    // [3][8] A_i[h] then [8] C[h]
#define WS_WVI  13984    // [4][128] f32  w_i·Wv[:,hd] (i=3 -> b)
#define WS_PEA  14496    // [8][101] f32  pe[l]·a_h
#define WS_PEH  15304    // f16 [101][128] pos-enc
#define WS_PVH  21768    // f16 [128][104] PV[hd][l] = pe[l]·Wv[:,hd], l>=101 zero
#define WS_WCT  28424    // f16 [128][128] WcwT[e][hd] = Wcw[hd][e]
// end: 36616 floats = 146 KB

__device__ __forceinline__ unsigned f2key(float x) {
    unsigned u = __float_as_uint(x);
    return (u & 0x80000000u) ? ~u : (u | 0x80000000u);
}
__device__ __forceinline__ float key2f(unsigned k) {
    unsigned u = (k & 0x80000000u) ? (k & 0x7fffffffu) : ~k;
    return __uint_as_float(u);
}
__device__ __forceinline__ void dot8(float& c0, float& c1, float& c2, float& c3,
                                     half8v p, half8v a) {
    c0 = __builtin_amdgcn_fdot2(__builtin_shufflevector(p, p, 0, 1),
                                __builtin_shufflevector(a, a, 0, 1), c0, false);
    c1 = __builtin_amdgcn_fdot2(__builtin_shufflevector(p, p, 2, 3),
                                __builtin_shufflevector(a, a, 2, 3), c1, false);
    c2 = __builtin_amdgcn_fdot2(__builtin_shufflevector(p, p, 4, 5),
                                __builtin_shufflevector(a, a, 4, 5), c2, false);
    c3 = __builtin_amdgcn_fdot2(__builtin_shufflevector(p, p, 6, 7),
                                __builtin_shufflevector(a, a, 6, 7), c3, false);
}

// ---- S1: q, a, A/C (block 0); pe tables + WVi (blocks 1..55)
__global__ void setup1(const float* __restrict__ cur, const float* __restrict__ Wq,
                       const float* __restrict__ Wk, const float* __restrict__ iw,
                       const float* __restrict__ ib, const float* __restrict__ Wv,
                       float* __restrict__ ws) {
    const int t = threadIdx.x, b = blockIdx.x;
    if (b == 0) {
        __shared__ float qs[EMB];
        __shared__ float as_[Hh * EMB];
        if (t < EMB) {
            float acc = 0.f;
            for (int e = 0; e < EMB; ++e) acc += cur[e] * Wq[e * EMB + t];
            qs[t] = acc;
        }
        __syncthreads();
        for (int i = t; i < Hh * EMB; i += TPB) {
            int h = i >> 7, e = i & 127;
            float acc = 0.f;
            for (int d = 0; d < 16; ++d) acc += Wk[e * EMB + h * 16 + d] * qs[h * 16 + d];
            acc *= 0.25f;
            as_[i] = acc; ws[WS_A + i] = acc;
        }
        __syncthreads();
        if (t < 32) {
            int i = t >> 3, h = t & 7;
            const float* src = (i == 0) ? iw : (i == 1) ? iw + EMB : (i == 2) ? iw + 2 * EMB : ib;
            float acc = 0.f;
            for (int e = 0; e < EMB; ++e) acc += src[e] * as_[h * EMB + e];
            ws[WS_AC + t] = acc;
        }
    } else {
        int base = (b - 1) * TPB + t;
        const float kneg = -0.14619587891040738f;  // -ln(10000)/63
        if (base < LL * EMB) {
            int l = base >> 7, c = base & 127, ic = c & 63;
            float inv = expf((float)ic * kneg);
            float v = (float)l * inv;
            float r = (c < 64) ? sinf(v) : cosf(v);
            ws[WS_PE + base] = r;
            ((_Float16*)(ws + WS_PEH))[base] = (_Float16)r;
        } else if (base < LL * EMB + 512) {
            int j = base - LL * EMB;
            int iv = j >> 7, hd = j & 127;
            const float* src = (iv == 0) ? iw : (iv == 1) ? iw + EMB : (iv == 2) ? iw + 2 * EMB : ib;
            float acc = 0.f;
            for (int e = 0; e < EMB; ++e) acc += src[e] * Wv[e * EMB + hd];
            ws[WS_WVI + j] = acc;
        }
    }
}

// ---- S2a: PVH f16 [128][104] (pad zero) + PEA f32 [8][101]
__global__ void setup2a(const float* __restrict__ Wv, float* __restrict__ ws) {
    int idx = blockIdx.x * TPB + threadIdx.x;
    if (idx < 128 * 104) {
        int hd = idx / 104, l = idx - hd * 104;
        float acc = 0.f;
        if (l < LL) {
            const float* pr = ws + WS_PE + l * EMB;
            for (int e = 0; e < EMB; ++e) acc += pr[e] * Wv[e * EMB + hd];
        }
        ((_Float16*)(ws + WS_PVH))[idx] = (_Float16)acc;
    } else if (idx < 128 * 104 + Hh * LL) {
        int j = idx - 128 * 104;
        int h = j / LL, l = j - h * LL;
        const float* pr = ws + WS_PE + l * EMB;
        const float* ar = ws + WS_A + h * EMB;
        float acc = 0.f;
        for (int e = 0; e < EMB; ++e) acc += pr[e] * ar[e];
        ws[WS_PEA + j] = acc;
    }
}

// ---- S2b: WcwT f16 [128][128]
__global__ void setup2b(const float* __restrict__ Wcw, float* __restrict__ ws) {
    int idx = blockIdx.x * TPB + threadIdx.x;
    if (idx < 128 * 128) {
        int e = idx >> 7, hd = idx & 127;
        ((_Float16*)(ws + WS_WCT))[idx] = (_Float16)Wcw[hd * EMB + e];
    }
}

__global__ __launch_bounds__(TPB, 8) void main_kernel(
    const float* __restrict__ dist,
    const float* __restrict__ xy,
    const float* __restrict__ ndem,
    const float* __restrict__ ninf,
    const float* __restrict__ iw,
    const float* __restrict__ ib,
    const float* __restrict__ Wcb,
    const float* __restrict__ ws,
    float* __restrict__ out) {

    const int bw   = blockIdx.x;
    const int tid  = threadIdx.x;
    const int lane = tid & 63;
    const int wid  = tid >> 6;
    const float* distRow = dist + (size_t)bw * Nn;
    const float* maskRow = ninf + (size_t)bw * Nn;
    float*       outRow  = out  + (size_t)bw * Nn;

    // u0: radix histograms (select phase) | output row buffer (final phase)
    __shared__ __align__(16) char u0[4096];
    int*   hist4 = (int*)u0;        // [4][256]
    float* row   = (float*)u0;      // [1000]

    __shared__ unsigned long long list[104];
    __shared__ int   sel[LL];                 // idx | 0x40000000 inf-flag
    __shared__ float feat3[3 * LL];           // sx | sy | sdem
    __shared__ float smk[LL];
    __shared__ __align__(16) _Float16 attnh[Hh * 104];  // f16 attn rows, pad 101..103 = 0
    __shared__ __align__(16) _Float16 uhh[EMB];
    __shared__ float mhf[EMB];
    __shared__ __align__(16) _Float16 mhh[EMB];
    __shared__ float cAC[32];
    __shared__ float coef[Hh][3];
    __shared__ float coefM[4];
    __shared__ int   selSh[3];
    __shared__ int   waveSums[4];
    __shared__ float red[2];
    __shared__ unsigned long long pivotSh;
    __shared__ int   cntSh;

    // ---- keys in registers: (orderable(dist_eff) << 32) | index; depot & pad = MAX
    unsigned long long rk[4];
    #pragma unroll
    for (int r = 0; r < 4; ++r) {
        int i = tid + 256 * r;
        unsigned long long kv = ~0ull;
        if (i >= 1 && i < Nn) {
            float de = distRow[i] - maskRow[i];
            kv = ((unsigned long long)f2key(de) << 32) | (unsigned)i;
        }
        rk[r] = kv;
    }
    #pragma unroll
    for (int r = 0; r < 4; ++r) hist4[tid + 256 * r] = 0;
    __syncthreads();

    // ---- exact radix select (MSB-first): key of 0-based rank 99 (keys unique)
    unsigned long long prefix = 0;
    int shift = 56;
    int remRank = 99;
    int* myhist = hist4 + (wid << 8);
    for (int round = 0; round < 8; ++round) {
        shift = 56 - 8 * round;
        #pragma unroll
        for (int r = 0; r < 4; ++r) {
            unsigned long long kv = rk[r];
            if (round == 0 || (kv >> (shift + 8)) == (prefix >> (shift + 8)))
                atomicAdd(&myhist[(unsigned)((kv >> shift) & 0xffull)], 1);
        }
        __syncthreads();
        int cnt = hist4[tid] + hist4[256 + tid] + hist4[512 + tid] + hist4[768 + tid];
        hist4[tid] = 0; hist4[256 + tid] = 0; hist4[512 + tid] = 0; hist4[768 + tid] = 0;
        int v = cnt;
        #pragma unroll
        for (int o = 1; o < 64; o <<= 1) {
            int t = __shfl_up(v, o, 64);
            if (lane >= o) v += t;
        }
        if (lane == 63) waveSums[wid] = v;
        __syncthreads();
        int wOff = 0;
        if (wid > 0) wOff += waveSums[0];
        if (wid > 1) wOff += waveSums[1];
        if (wid > 2) wOff += waveSums[2];
        int excl = v + wOff - cnt;
        if (cnt > 0 && remRank >= excl && remRank < excl + cnt) {
            selSh[0] = tid; selSh[1] = excl; selSh[2] = cnt;
        }
        __syncthreads();
        prefix |= ((unsigned long long)selSh[0]) << shift;
        remRank -= selSh[1];
        if (selSh[2] == 1) break;
    }
    #pragma unroll
    for (int r = 0; r < 4; ++r)
        if ((rk[r] >> shift) == (prefix >> shift)) pivotSh = rk[r];
    if (tid == 0) cntSh = 0;
    __syncthreads();
    const unsigned long long pivot = pivotSh;

    // ---- ballot-compact the 100 keys <= pivot (unordered)
    #pragma unroll
    for (int r = 0; r < 4; ++r) {
        bool p = rk[r] <= pivot;
        unsigned long long m = __ballot(p);
        int c = __popcll(m);
        int base = 0;
        if (lane == 0 && c) base = atomicAdd(&cntSh, c);
        base = __shfl(base, 0, 64);
        if (p) list[base + __popcll(m & ((1ull << lane) - 1ull))] = rk[r];
    }
    __syncthreads();

    // ---- parallel rank + norm max (waves 0-1); zero LDS row buffer (waves 2-3)
    if (tid < 128) {
        float dvm = 0.f;
        if (tid < LOCALK) {
            unsigned long long kv = list[tid];
            int rank = 0;
            for (int j = 0; j < LOCALK; ++j) rank += (list[j] < kv) ? 1 : 0;
            float v = key2f((unsigned)(kv >> 32));
            bool infm = isinf(v);
            sel[rank + 1] = (int)(unsigned)(kv & 0xffffffffu) | (infm ? 0x40000000 : 0);
            dvm = infm ? 0.f : v;
        }
        #pragma unroll
        for (int o = 32; o > 0; o >>= 1) dvm = fmaxf(dvm, __shfl_xor(dvm, o, 64));
        if (lane == 0) red[wid] = dvm;
    } else {
        float4 z = make_float4(0.f, 0.f, 0.f, 0.f);
        float4* r4 = (float4*)row;
        for (int i = tid - 128; i < 250; i += 128) r4[i] = z;
    }
    if (tid == 0) sel[0] = 0x40000000;
    __syncthreads();

    const float nmax = fmaxf(red[0], red[1]);
    const bool  norm_on = (nmax != 0.f);
    const float nfac = nmax + 1e-6f;

    // ---- gather features (+ load A/C consts into LDS)
    if (tid < LL) {
        int s = sel[tid];
        int n = s & 0xffffff;
        bool infm = (s & 0x40000000) != 0;
        float fx = 0.f, fy = 0.f, fd = 0.f;
        if (!infm) {
            size_t base = (size_t)bw * Nn + n;
            fx = xy[2 * base];
            fy = xy[2 * base + 1];
            fd = ndem[base];
        }
        if (norm_on) { fx /= nfac; fy /= nfac; }
        feat3[tid] = fx; feat3[LL + tid] = fy; feat3[2 * LL + tid] = fd;
        smk[tid] = maskRow[n];
    }
    if (tid >= 224) cAC[tid - 224] = ws[WS_AC + tid - 224];
    __syncthreads();

    // ---- fused scores + softmax + coef: group g (32 lanes) owns head g
    {
        int g = tid >> 5, ln = tid & 31;
        int l0 = ln, l1 = ln + 32, l2 = ln + 64, l3 = ln + 96;
        bool ok3 = (l3 < LL);
        const float* pea = ws + WS_PEA + g * LL;
        float A0 = cAC[g], A1 = cAC[8 + g], A2 = cAC[16 + g], C = cAC[24 + g];
        float v0 = feat3[l0] * A0 + feat3[LL + l0] * A1 + feat3[2 * LL + l0] * A2 + C + pea[l0] + smk[l0];
        float v1 = feat3[l1] * A0 + feat3[LL + l1] * A1 + feat3[2 * LL + l1] * A2 + C + pea[l1] + smk[l1];
        float v2 = feat3[l2] * A0 + feat3[LL + l2] * A1 + feat3[2 * LL + l2] * A2 + C + pea[l2] + smk[l2];
        float v3 = ok3 ? (feat3[l3] * A0 + feat3[LL + l3] * A1 + feat3[2 * LL + l3] * A2 + C + pea[l3] + smk[l3])
                       : -INFINITY;
        float m = fmaxf(fmaxf(v0, v1), fmaxf(v2, v3));
        #pragma unroll
        for (int o = 16; o > 0; o >>= 1) m = fmaxf(m, __shfl_xor(m, o, 32));
        float e0 = __expf(v0 - m), e1 = __expf(v1 - m), e2 = __expf(v2 - m);
        float e3 = ok3 ? __expf(v3 - m) : 0.f;
        float s = e0 + e1 + e2 + e3;
        #pragma unroll
        for (int o = 16; o > 0; o >>= 1) s += __shfl_xor(s, o, 32);
        float inv = 1.f / s;
        e0 *= inv; e1 *= inv; e2 *= inv; e3 *= inv;
        attnh[g * 104 + l0] = (_Float16)e0;
        attnh[g * 104 + l1] = (_Float16)e1;
        attnh[g * 104 + l2] = (_Float16)e2;
        if (ok3) attnh[g * 104 + l3] = (_Float16)e3;
        else if (l3 < 104) attnh[g * 104 + l3] = (_Float16)0.f;
        // coef[g][f] = sum_l attn[g][l] * feat3[f][l]  (exact f32, attn in regs)
        #pragma unroll
        for (int f = 0; f < 3; ++f) {
            const float* fr = feat3 + f * LL;
            float cs = e0 * fr[l0] + e1 * fr[l1] + e2 * fr[l2] + (ok3 ? e3 * fr[l3] : 0.f);
            #pragma unroll
            for (int o = 16; o > 0; o >>= 1) cs += __shfl_xor(cs, o, 32);
            if (ln == 0) coef[g][f] = cs;
        }
    }
    __syncthreads();

    // ---- u[hd] = attn[h] . PV[hd] + rank-3 corrections  (128 threads, 13 tiles)
    if (tid < 128) {
        int hd = tid, h = hd >> 4;
        const half8v* pv = (const half8v*)((const _Float16*)(ws + WS_PVH) + hd * 104);
        const half8v* at = (const half8v*)(attnh + h * 104);
        float c0 = 0.f, c1 = 0.f, c2 = 0.f, c3 = 0.f;
        #pragma unroll
        for (int j = 0; j < 13; ++j) dot8(c0, c1, c2, c3, pv[j], at[j]);
        float u = (c0 + c1) + (c2 + c3)
                + coef[h][0] * ws[WS_WVI + hd]
                + coef[h][1] * ws[WS_WVI + 128 + hd]
                + coef[h][2] * ws[WS_WVI + 256 + hd]
                + ws[WS_WVI + 384 + hd];
        uhh[hd] = (_Float16)u;
    }
    __syncthreads();

    // ---- mh[e] = Wcb[e] + u . WcwT[e]  (128 threads, 16 tiles)
    if (tid < 128) {
        int e = tid;
        const half8v* wr = (const half8v*)((const _Float16*)(ws + WS_WCT) + e * 128);
        const half8v* ur = (const half8v*)uhh;
        float c0 = 0.f, c1 = 0.f, c2 = 0.f, c3 = 0.f;
        #pragma unroll
        for (int j = 0; j < 16; ++j) dot8(c0, c1, c2, c3, wr[j], ur[j]);
        float m = Wcb[e] + (c0 + c1) + (c2 + c3);
        mhf[e] = m; mhh[e] = (_Float16)m;
    }
    __syncthreads();

    // ---- coefM[g] = mh . {w0,w1,w2,b}
    {
        int g = tid >> 6;
        const float* src = (g == 0) ? iw : (g == 1) ? iw + EMB : (g == 2) ? iw + 2 * EMB : ib;
        float v = mhf[lane] * src[lane] + mhf[lane + 64] * src[lane + 64];
        #pragma unroll
        for (int o = 32; o > 0; o >>= 1) v += __shfl_xor(v, o, 64);
        if (lane == 0) coefM[g] = v;
    }
    __syncthreads();

    // ---- score2[l] = (base + mh.pe[l]) / sqrt(128); scatter into LDS row
    if (tid < LL) {
        float base = feat3[tid] * coefM[0] + feat3[LL + tid] * coefM[1]
                   + feat3[2 * LL + tid] * coefM[2] + coefM[3];
        const half8v* pr = (const half8v*)((const _Float16*)(ws + WS_PEH) + tid * 128);
        const half8v* mr = (const half8v*)mhh;
        float c0 = 0.f, c1 = 0.f, c2 = 0.f, c3 = 0.f;
        #pragma unroll
        for (int j = 0; j < 16; ++j) dot8(c0, c1, c2, c3, pr[j], mr[j]);
        row[sel[tid] & 0xffffff] = (base + (c0 + c1) + (c2 + c3)) * 0.08838834764831845f;
    }
    __syncthreads();

    // ---- stream the whole row out coalesced (covers all 1000 elements)
    if (tid < 250) {
        ((float4*)outRow)[tid] = ((float4*)row)[tid];
    }
}

extern "C" void kernel_launch(void* const* d_in, const int* in_sizes, int n_in,
                              void* d_out, int out_size, void* d_ws, size_t ws_size,
                              hipStream_t stream) {
    // 0 theta, 1 dist, 2 xy, 3 norm_demand, 4 ninf_mask,
    // 5 init_w, 6 init_b, 7 cur_token, 8 Wq, 9 Wk, 10 Wv, 11 Wc_w, 12 Wc_b
    const float* dist  = (const float*)d_in[1];
    const float* xy    = (const float*)d_in[2];
    const float* ndem  = (const float*)d_in[3];
    const float* ninf  = (const float*)d_in[4];
    const float* initw = (const float*)d_in[5];
    const float* initb = (const float*)d_in[6];
    const float* cur   = (const float*)d_in[7];
    const float* Wq    = (const float*)d_in[8];
    const float* Wk    = (const float*)d_in[9];
    const float* Wv    = (const float*)d_in[10];
    const float* Wcw   = (const float*)d_in[11];
    const float* Wcb   = (const float*)d_in[12];
    float* out = (float*)d_out;
    float* ws  = (float*)d_ws;

    hipLaunchKernelGGL(setup1,  dim3(56), dim3(TPB), 0, stream, cur, Wq, Wk, initw, initb, Wv, ws);
    hipLaunchKernelGGL(setup2a, dim3(56), dim3(TPB), 0, stream, Wv, ws);
    hipLaunchKernelGGL(setup2b, dim3(64), dim3(TPB), 0, stream, Wcw, ws);
    hipLaunchKernelGGL(main_kernel, dim3(Bb * Ww), dim3(TPB), 0, stream,
                       dist, xy, ndem, ninf, initw, initb, Wcb, ws, out);
}

// Round 7
// 101.898 us; speedup vs baseline: 6.0377x; 1.0250x over previous
//
#include <hip/hip_runtime.h>
#include <math.h>

#define Bb   48
#define Ww   100
#define Nn   1000
#define EMB  128
#define Hh   8
#define LL   101     // depot + 100 neighbors
#define LOCALK 100
#define TPB  256
#define PPB  4       // problems (waves) per block

typedef _Float16 half2v __attribute__((ext_vector_type(2)));
typedef _Float16 half8v __attribute__((ext_vector_type(8)));

// ---- workspace layout (float offsets) — unchanged from R6
#define WS_A    0        // [8][128] f32  a_h = (Wk q_h)/4
#define WS_PE   1024     // [101][128] f32 pos-enc
#define WS_AC   13952    // [3][8] A_i[h] then [8] C[h]
#define WS_WVI  13984    // [4][128] f32  w_i·Wv[:,hd] (i=3 -> b)
#define WS_PEA  14496    // [8][101] f32  pe[l]·a_h
#define WS_PEH  15304    // f16 [101][128] pos-enc
#define WS_PVH  21768    // f16 [128][104] PV[hd][l] = pe[l]·Wv[:,hd], l>=101 zero
#define WS_WCT  28424    // f16 [128][128] WcwT[e][hd] = Wcw[hd][e]

// per-problem LDS arena (bytes). A region is time-multiplexed:
//   phase select: hist[256]i32 @0, list[100]u64 @1024
//   phase attn  : attnh[8][112]f16 @0 (1792B), uhh[128]f16 @1792
//   phase out   : row[1000]f32 @0
#define AR_SIZE 6528
#define AR_SEL  4096     // int[101]
#define AR_F3   4512     // float[303]
#define AR_SMK  5728     // float[101]
#define AR_MHH  6144     // f16[128]
#define AR_COEF 6400     // float[8][3]
#define AR_CM   6496     // float[4]

// wave-synchronous LDS: DS pipe is in-order per wave; fence the compiler.
#define WSYNC() do { __builtin_amdgcn_wave_barrier(); asm volatile("" ::: "memory"); } while (0)

__device__ __forceinline__ unsigned f2key(float x) {
    unsigned u = __float_as_uint(x);
    return (u & 0x80000000u) ? ~u : (u | 0x80000000u);
}
__device__ __forceinline__ float key2f(unsigned k) {
    unsigned u = (k & 0x80000000u) ? (k & 0x7fffffffu) : ~k;
    return __uint_as_float(u);
}
__device__ __forceinline__ void dot8(float& c0, float& c1, float& c2, float& c3,
                                     half8v p, half8v a) {
    c0 = __builtin_amdgcn_fdot2(__builtin_shufflevector(p, p, 0, 1),
                                __builtin_shufflevector(a, a, 0, 1), c0, false);
    c1 = __builtin_amdgcn_fdot2(__builtin_shufflevector(p, p, 2, 3),
                                __builtin_shufflevector(a, a, 2, 3), c1, false);
    c2 = __builtin_amdgcn_fdot2(__builtin_shufflevector(p, p, 4, 5),
                                __builtin_shufflevector(a, a, 4, 5), c2, false);
    c3 = __builtin_amdgcn_fdot2(__builtin_shufflevector(p, p, 6, 7),
                                __builtin_shufflevector(a, a, 6, 7), c3, false);
}

// ---- S1: q, a, A/C (block 0); pe tables + WVi (blocks 1..55)
__global__ void setup1(const float* __restrict__ cur, const float* __restrict__ Wq,
                       const float* __restrict__ Wk, const float* __restrict__ iw,
                       const float* __restrict__ ib, const float* __restrict__ Wv,
                       float* __restrict__ ws) {
    const int t = threadIdx.x, b = blockIdx.x;
    if (b == 0) {
        __shared__ float qs[EMB];
        __shared__ float as_[Hh * EMB];
        if (t < EMB) {
            float acc = 0.f;
            for (int e = 0; e < EMB; ++e) acc += cur[e] * Wq[e * EMB + t];
            qs[t] = acc;
        }
        __syncthreads();
        for (int i = t; i < Hh * EMB; i += TPB) {
            int h = i >> 7, e = i & 127;
            float acc = 0.f;
            for (int d = 0; d < 16; ++d) acc += Wk[e * EMB + h * 16 + d] * qs[h * 16 + d];
            acc *= 0.25f;
            as_[i] = acc; ws[WS_A + i] = acc;
        }
        __syncthreads();
        if (t < 32) {
            int i = t >> 3, h = t & 7;
            const float* src = (i == 0) ? iw : (i == 1) ? iw + EMB : (i == 2) ? iw + 2 * EMB : ib;
            float acc = 0.f;
            for (int e = 0; e < EMB; ++e) acc += src[e] * as_[h * EMB + e];
            ws[WS_AC + t] = acc;
        }
    } else {
        int base = (b - 1) * TPB + t;
        const float kneg = -0.14619587891040738f;  // -ln(10000)/63
        if (base < LL * EMB) {
            int l = base >> 7, c = base & 127, ic = c & 63;
            float inv = expf((float)ic * kneg);
            float v = (float)l * inv;
            float r = (c < 64) ? sinf(v) : cosf(v);
            ws[WS_PE + base] = r;
            ((_Float16*)(ws + WS_PEH))[base] = (_Float16)r;
        } else if (base < LL * EMB + 512) {
            int j = base - LL * EMB;
            int iv = j >> 7, hd = j & 127;
            const float* src = (iv == 0) ? iw : (iv == 1) ? iw + EMB : (iv == 2) ? iw + 2 * EMB : ib;
            float acc = 0.f;
            for (int e = 0; e < EMB; ++e) acc += src[e] * Wv[e * EMB + hd];
            ws[WS_WVI + j] = acc;
        }
    }
}

// ---- S2a: PVH f16 [128][104] (pad zero) + PEA f32 [8][101]
__global__ void setup2a(const float* __restrict__ Wv, float* __restrict__ ws) {
    int idx = blockIdx.x * TPB + threadIdx.x;
    if (idx < 128 * 104) {
        int hd = idx / 104, l = idx - hd * 104;
        float acc = 0.f;
        if (l < LL) {
            const float* pr = ws + WS_PE + l * EMB;
            for (int e = 0; e < EMB; ++e) acc += pr[e] * Wv[e * EMB + hd];
        }
        ((_Float16*)(ws + WS_PVH))[idx] = (_Float16)acc;
    } else if (idx < 128 * 104 + Hh * LL) {
        int j = idx - 128 * 104;
        int h = j / LL, l = j - h * LL;
        const float* pr = ws + WS_PE + l * EMB;
        const float* ar = ws + WS_A + h * EMB;
        float acc = 0.f;
        for (int e = 0; e < EMB; ++e) acc += pr[e] * ar[e];
        ws[WS_PEA + j] = acc;
    }
}

// ---- S2b: WcwT f16 [128][128]
__global__ void setup2b(const float* __restrict__ Wcw, float* __restrict__ ws) {
    int idx = blockIdx.x * TPB + threadIdx.x;
    if (idx < 128 * 128) {
        int e = idx >> 7, hd = idx & 127;
        ((_Float16*)(ws + WS_WCT))[idx] = (_Float16)Wcw[hd * EMB + e];
    }
}

__global__ __launch_bounds__(TPB, 6) void main_kernel(
    const float* __restrict__ dist,
    const float* __restrict__ xy,
    const float* __restrict__ ndem,
    const float* __restrict__ ninf,
    const float* __restrict__ iw,
    const float* __restrict__ ib,
    const float* __restrict__ Wcb,
    const float* __restrict__ ws,
    float* __restrict__ out) {

    __shared__ __align__(16) char smem[PPB][AR_SIZE];
    const int tid  = threadIdx.x;
    const int w    = tid >> 6;
    const int lane = tid & 63;
    const int bw   = blockIdx.x * PPB + w;    // 1200 * 4 = 4800 exact

    char* A = smem[w];
    int*                hist  = (int*)A;
    unsigned long long* list  = (unsigned long long*)(A + 1024);
    _Float16*           attnh = (_Float16*)A;              // [8][112]
    _Float16*           uhh   = (_Float16*)(A + 1792);     // [128]
    float*              row   = (float*)A;                 // [1000]
    int*                sel   = (int*)(A + AR_SEL);
    float*              feat3 = (float*)(A + AR_F3);
    float*              smk   = (float*)(A + AR_SMK);
    _Float16*           mhh   = (_Float16*)(A + AR_MHH);
    float*              coef  = (float*)(A + AR_COEF);     // [8][3]
    float*              coefM = (float*)(A + AR_CM);       // [4]

    const float* distRow = dist + (size_t)bw * Nn;
    const float* maskRow = ninf + (size_t)bw * Nn;

    // ---- keys in registers: 16 per lane
    unsigned long long rk[16];
    #pragma unroll
    for (int r = 0; r < 16; ++r) {
        int i = r * 64 + lane;
        unsigned long long kv = ~0ull;
        if (i >= 1 && i < Nn) {
            float de = distRow[i] - maskRow[i];
            kv = ((unsigned long long)f2key(de) << 32) | (unsigned)i;
        }
        rk[r] = kv;
    }
    ((int4*)hist)[lane] = make_int4(0, 0, 0, 0);
    WSYNC();

    // ---- exact radix select (MSB-first), wave-local, no barriers
    unsigned long long prefix = 0;
    int shift = 56;
    int remRank = 99;
    const unsigned long long ltm = (1ull << lane) - 1ull;
    for (int round = 0; round < 8; ++round) {
        shift = 56 - 8 * round;
        #pragma unroll
        for (int r = 0; r < 16; ++r) {
            unsigned long long kv = rk[r];
            bool in = (kv != ~0ull) &&
                      (round == 0 || (kv >> (shift + 8)) == (prefix >> (shift + 8)));
            if (in) atomicAdd(&hist[(unsigned)((kv >> shift) & 0xffull)], 1);
        }
        WSYNC();
        int4 hv = ((int4*)hist)[lane];          // buckets 4*lane .. +3
        ((int4*)hist)[lane] = make_int4(0, 0, 0, 0);   // re-zero for next round
        int s = hv.x + hv.y + hv.z + hv.w;
        int incl = s;
        #pragma unroll
        for (int o = 1; o < 64; o <<= 1) { int t = __shfl_up(incl, o, 64); if (lane >= o) incl += t; }
        int e0 = incl - s;
        int e1 = e0 + hv.x, e2 = e1 + hv.y, e3 = e2 + hv.z;
        int bc = -1, ec = 0, cc = 0;
        if (hv.x > 0 && remRank >= e0 && remRank < e1)        { bc = 4*lane+0; ec = e0; cc = hv.x; }
        if (hv.y > 0 && remRank >= e1 && remRank < e2)        { bc = 4*lane+1; ec = e1; cc = hv.y; }
        if (hv.z > 0 && remRank >= e2 && remRank < e3)        { bc = 4*lane+2; ec = e2; cc = hv.z; }
        if (hv.w > 0 && remRank >= e3 && remRank < e3+hv.w)   { bc = 4*lane+3; ec = e3; cc = hv.w; }
        unsigned long long fm = __ballot(bc >= 0);
        int srcl = __ffsll((unsigned long long)fm) - 1;
        bc = __shfl(bc, srcl, 64); ec = __shfl(ec, srcl, 64); cc = __shfl(cc, srcl, 64);
        prefix |= ((unsigned long long)(unsigned)bc) << shift;
        remRank -= ec;
        if (cc == 1) break;
    }

    // ---- pivot key (unique match on resolved prefix)
    unsigned long long pk = 0; bool pf = false;
    #pragma unroll
    for (int r = 0; r < 16; ++r)
        if ((rk[r] >> shift) == (prefix >> shift)) { pk = rk[r]; pf = true; }
    {
        unsigned long long fm = __ballot(pf);
        int srcl = __ffsll((unsigned long long)fm) - 1;
        pk = __shfl(pk, srcl, 64);
    }
    const unsigned long long pivot = pk;

    // ---- ballot-compact the 100 keys <= pivot (no atomics)
    int cnt_run = 0;
    #pragma unroll
    for (int r = 0; r < 16; ++r) {
        bool p = rk[r] <= pivot;
        unsigned long long m = __ballot(p);
        if (p) list[cnt_run + (int)__popcll(m & ltm)] = rk[r];
        cnt_run += (int)__popcll(m);
    }
    WSYNC();

    // ---- parallel rank + norm max (all in-wave)
    unsigned long long kv0 = list[lane];
    const bool has1 = lane < (LOCALK - 64);
    unsigned long long kv1 = has1 ? list[lane + 64] : ~0ull;
    int r0 = 0, r1 = 0;
    #pragma unroll 4
    for (int j = 0; j < LOCALK; ++j) {
        unsigned long long lv = list[j];
        r0 += (lv < kv0);
        r1 += (lv < kv1);
    }
    float v0 = key2f((unsigned)(kv0 >> 32));
    bool i0 = isinf(v0);
    sel[r0 + 1] = (int)(kv0 & 0xffffffu) | (i0 ? 0x40000000 : 0);
    float dvm = i0 ? 0.f : v0;
    if (has1) {
        float v1 = key2f((unsigned)(kv1 >> 32));
        bool i1 = isinf(v1);
        sel[r1 + 1] = (int)(kv1 & 0xffffffu) | (i1 ? 0x40000000 : 0);
        dvm = fmaxf(dvm, i1 ? 0.f : v1);
    }
    #pragma unroll
    for (int o = 32; o > 0; o >>= 1) dvm = fmaxf(dvm, __shfl_xor(dvm, o, 64));
    if (lane == 0) sel[0] = 0x40000000;      // depot: idx 0, inf-flag
    const float nmax = dvm;
    const bool  norm_on = (nmax != 0.f);
    const float nfac = nmax + 1e-6f;
    WSYNC();

    // ---- gather features
    auto gather1 = [&](int t) {
        int s = sel[t];
        int n = s & 0xffffff;
        bool infm = (s & 0x40000000) != 0;
        float fx = 0.f, fy = 0.f, fd = 0.f;
        if (!infm) {
            size_t base = (size_t)bw * Nn + n;
            fx = xy[2 * base]; fy = xy[2 * base + 1]; fd = ndem[base];
        }
        if (norm_on) { fx /= nfac; fy /= nfac; }
        feat3[t] = fx; feat3[LL + t] = fy; feat3[2 * LL + t] = fd;
        smk[t] = maskRow[n];
    };
    gather1(lane);
    if (lane < LL - 64) gather1(lane + 64);
    WSYNC();

    // ---- fused scores + softmax + coef: 8 lanes per head
    const int h = lane >> 3, ln8 = lane & 7;
    {
        const float A0 = ws[WS_AC + h], A1 = ws[WS_AC + 8 + h];
        const float A2 = ws[WS_AC + 16 + h], Cc = ws[WS_AC + 24 + h];
        const float* pea = ws + WS_PEA + h * LL;
        float ev[14];
        float mx = -INFINITY;
        #pragma unroll
        for (int k = 0; k < 14; ++k) {
            int l = ln8 + 8 * k;
            float sv = -INFINITY;
            if (l < LL)
                sv = feat3[l] * A0 + feat3[LL + l] * A1 + feat3[2 * LL + l] * A2
                   + Cc + pea[l] + smk[l];
            ev[k] = sv;
            mx = fmaxf(mx, sv);
        }
        #pragma unroll
        for (int o = 1; o < 8; o <<= 1) mx = fmaxf(mx, __shfl_xor(mx, o, 64));
        float sm = 0.f;
        #pragma unroll
        for (int k = 0; k < 14; ++k) {
            int l = ln8 + 8 * k;
            float e = (l < LL) ? __expf(ev[k] - mx) : 0.f;
            ev[k] = e; sm += e;
        }
        #pragma unroll
        for (int o = 1; o < 8; o <<= 1) sm += __shfl_xor(sm, o, 64);
        const float ainv = 1.f / sm;
        #pragma unroll
        for (int k = 0; k < 14; ++k) {
            int l = ln8 + 8 * k;                 // l <= 111 always
            attnh[h * 112 + l] = (_Float16)(ev[k] * ainv);
        }
        float c0 = 0.f, c1 = 0.f, c2 = 0.f;
        #pragma unroll
        for (int k = 0; k < 13; ++k) {
            int l = ln8 + 8 * k;
            if (l < LL) {
                float at = ev[k] * ainv;
                c0 += at * feat3[l]; c1 += at * feat3[LL + l]; c2 += at * feat3[2 * LL + l];
            }
        }
        #pragma unroll
        for (int o = 1; o < 8; o <<= 1) {
            c0 += __shfl_xor(c0, o, 64); c1 += __shfl_xor(c1, o, 64); c2 += __shfl_xor(c2, o, 64);
        }
        if (ln8 == 0) { coef[h * 3 + 0] = c0; coef[h * 3 + 1] = c1; coef[h * 3 + 2] = c2; }
    }
    WSYNC();

    // ---- u[hd] = attn[h] . PV[hd] + rank-3 corrections
    #pragma unroll
    for (int t = 0; t < 2; ++t) {
        int hd = lane + 64 * t;
        int hh = hd >> 4;
        const half8v* pv = (const half8v*)((const _Float16*)(ws + WS_PVH) + hd * 104);
        const half8v* at = (const half8v*)(attnh + hh * 112);
        float d0 = 0.f, d1 = 0.f, d2 = 0.f, d3 = 0.f;
        #pragma unroll
        for (int j = 0; j < 13; ++j) dot8(d0, d1, d2, d3, pv[j], at[j]);
        float u = (d0 + d1) + (d2 + d3)
                + coef[hh * 3 + 0] * ws[WS_WVI + hd]
                + coef[hh * 3 + 1] * ws[WS_WVI + 128 + hd]
                + coef[hh * 3 + 2] * ws[WS_WVI + 256 + hd]
                + ws[WS_WVI + 384 + hd];
        uhh[hd] = (_Float16)u;
    }
    WSYNC();

    // ---- mh[e] = Wcb[e] + u . WcwT[e]
    #pragma unroll
    for (int t = 0; t < 2; ++t) {
        int e = lane + 64 * t;
        const half8v* wr = (const half8v*)((const _Float16*)(ws + WS_WCT) + e * 128);
        const half8v* ur = (const half8v*)uhh;
        float d0 = 0.f, d1 = 0.f, d2 = 0.f, d3 = 0.f;
        #pragma unroll
        for (int j = 0; j < 16; ++j) dot8(d0, d1, d2, d3, wr[j], ur[j]);
        mhh[e] = (_Float16)(Wcb[e] + (d0 + d1) + (d2 + d3));
    }
    WSYNC();

    // ---- coefM[g] = mh . {w0,w1,w2,b}   (16 lanes per g)
    {
        int g = lane & 3;
        const float* src = (g == 0) ? iw : (g == 1) ? iw + EMB : (g == 2) ? iw + 2 * EMB : ib;
        float v = 0.f;
        #pragma unroll
        for (int j = 0; j < 8; ++j) {
            int e = (lane >> 2) + 16 * j;
            v += (float)mhh[e] * src[e];
        }
        v += __shfl_xor(v, 4, 64); v += __shfl_xor(v, 8, 64);
        v += __shfl_xor(v, 16, 64); v += __shfl_xor(v, 32, 64);
        if (lane < 4) coefM[lane] = v;
    }
    // zero LDS row (attnh/uhh/hist/list all dead now)
    {
        float4 z = make_float4(0.f, 0.f, 0.f, 0.f);
        ((float4*)row)[lane] = z;
        ((float4*)row)[lane + 64] = z;
        ((float4*)row)[lane + 128] = z;
        if (lane < 58) ((float4*)row)[lane + 192] = z;
    }
    WSYNC();

    // ---- score2[l] = (base + mh.pe[l]) / sqrt(128); scatter into LDS row
    auto score2 = [&](int t) {
        float base = feat3[t] * coefM[0] + feat3[LL + t] * coefM[1]
                   + feat3[2 * LL + t] * coefM[2] + coefM[3];
        const half8v* pr = (const half8v*)((const _Float16*)(ws + WS_PEH) + t * 128);
        const half8v* mr = (const half8v*)mhh;
        float d0 = 0.f, d1 = 0.f, d2 = 0.f, d3 = 0.f;
        #pragma unroll
        for (int j = 0; j < 16; ++j) dot8(d0, d1, d2, d3, pr[j], mr[j]);
        row[sel[t] & 0xffffff] = (base + (d0 + d1) + (d2 + d3)) * 0.08838834764831845f;
    };
    score2(lane);
    if (lane < LL - 64) score2(lane + 64);
    WSYNC();

    // ---- stream the row out coalesced
    float* outRow = out + (size_t)bw * Nn;
    ((float4*)outRow)[lane]       = ((float4*)row)[lane];
    ((float4*)outRow)[lane + 64]  = ((float4*)row)[lane + 64];
    ((float4*)outRow)[lane + 128] = ((float4*)row)[lane + 128];
    if (lane < 58) ((float4*)outRow)[lane + 192] = ((float4*)row)[lane + 192];
}

extern "C" void kernel_launch(void* const* d_in, const int* in_sizes, int n_in,
                              void* d_out, int out_size, void* d_ws, size_t ws_size,
                              hipStream_t stream) {
    // 0 theta, 1 dist, 2 xy, 3 norm_demand, 4 ninf_mask,
    // 5 init_w, 6 init_b, 7 cur_token, 8 Wq, 9 Wk, 10 Wv, 11 Wc_w, 12 Wc_b
    const float* dist  = (const float*)d_in[1];
    const float* xy    = (const float*)d_in[2];
    const float* ndem  = (const float*)d_in[3];
    const float* ninf  = (const float*)d_in[4];
    const float* initw = (const float*)d_in[5];
    const float* initb = (const float*)d_in[6];
    const float* cur   = (const float*)d_in[7];
    const float* Wq    = (const float*)d_in[8];
    const float* Wk    = (const float*)d_in[9];
    const float* Wv    = (const float*)d_in[10];
    const float* Wcw   = (const float*)d_in[11];
    const float* Wcb   = (const float*)d_in[12];
    float* out = (float*)d_out;
    float* ws  = (float*)d_ws;

    hipLaunchKernelGGL(setup1,  dim3(56), dim3(TPB), 0, stream, cur, Wq, Wk, initw, initb, Wv, ws);
    hipLaunchKernelGGL(setup2a, dim3(56), dim3(TPB), 0, stream, Wv, ws);
    hipLaunchKernelGGL(setup2b, dim3(64), dim3(TPB), 0, stream, Wcw, ws);
    hipLaunchKernelGGL(main_kernel, dim3(Bb * Ww / PPB), dim3(TPB), 0, stream,
                       dist, xy, ndem, ninf, initw, initb, Wcb, ws, out);
}

// Round 8
// 101.319 us; speedup vs baseline: 6.0722x; 1.0057x over previous
//
#include <hip/hip_runtime.h>
#include <math.h>

#define Bb   48
#define Ww   100
#define Nn   1000
#define EMB  128
#define Hh   8
#define LL   101     // depot + 100 neighbors
#define LOCALK 100
#define TPB  128
#define PPB  2       // problems (waves) per block

typedef _Float16 half2v __attribute__((ext_vector_type(2)));
typedef _Float16 half8v __attribute__((ext_vector_type(8)));

// ---- workspace layout (float offsets) — unchanged from R6/R7
#define WS_A    0        // [8][128] f32  a_h = (Wk q_h)/4
#define WS_PE   1024     // [101][128] f32 pos-enc
#define WS_AC   13952    // [3][8] A_i[h] then [8] C[h]
#define WS_WVI  13984    // [4][128] f32  w_i·Wv[:,hd] (i=3 -> b)
#define WS_PEA  14496    // [8][101] f32  pe[l]·a_h
#define WS_PEH  15304    // f16 [101][128] pos-enc
#define WS_PVH  21768    // f16 [128][104] PV[hd][l] = pe[l]·Wv[:,hd], l>=101 zero
#define WS_WCT  28424    // f16 [128][128] WcwT[e][hd] = Wcw[hd][e]

// per-problem LDS arena (bytes), regions time-multiplexed:
//  select : hist4[4][260]i32 @0 (4160) , list[100]u64 @4288
//  attn   : attnh[8][112]f16 @0 (1792) , uhh[128]f16 @1792
//  out    : row[1000]f32 @0 (4000)
//  stable : sel@5088 i32[101], perm@5492 u8[100], smk@5592 f32[101],
//           feat3@5996 f32[303], mhh@7216 f16[128], coef@7472 f32[24], coefM@7568 f32[4]
#define AR_SIZE 7584

#define WSYNC() do { __builtin_amdgcn_wave_barrier(); asm volatile("" ::: "memory"); } while (0)

__device__ __forceinline__ unsigned f2key(float x) {
    unsigned u = __float_as_uint(x);
    return (u & 0x80000000u) ? ~u : (u | 0x80000000u);
}
__device__ __forceinline__ float key2f(unsigned k) {
    unsigned u = (k & 0x80000000u) ? (k & 0x7fffffffu) : ~k;
    return __uint_as_float(u);
}
__device__ __forceinline__ void dot8(float& c0, float& c1, float& c2, float& c3,
                                     half8v p, half8v a) {
    c0 = __builtin_amdgcn_fdot2(__builtin_shufflevector(p, p, 0, 1),
                                __builtin_shufflevector(a, a, 0, 1), c0, false);
    c1 = __builtin_amdgcn_fdot2(__builtin_shufflevector(p, p, 2, 3),
                                __builtin_shufflevector(a, a, 2, 3), c1, false);
    c2 = __builtin_amdgcn_fdot2(__builtin_shufflevector(p, p, 4, 5),
                                __builtin_shufflevector(a, a, 4, 5), c2, false);
    c3 = __builtin_amdgcn_fdot2(__builtin_shufflevector(p, p, 6, 7),
                                __builtin_shufflevector(a, a, 6, 7), c3, false);
}

// ---- S1: q, a, A/C (block 0); pe tables + WVi (blocks 1..)
__global__ void setup1(const float* __restrict__ cur, const float* __restrict__ Wq,
                       const float* __restrict__ Wk, const float* __restrict__ iw,
                       const float* __restrict__ ib, const float* __restrict__ Wv,
                       float* __restrict__ ws) {
    const int t = threadIdx.x, b = blockIdx.x;
    if (b == 0) {
        __shared__ float qs[EMB];
        __shared__ float as_[Hh * EMB];
        if (t < EMB) {
            float acc = 0.f;
            for (int e = 0; e < EMB; ++e) acc += cur[e] * Wq[e * EMB + t];
            qs[t] = acc;
        }
        __syncthreads();
        for (int i = t; i < Hh * EMB; i += 256) {
            int h = i >> 7, e = i & 127;
            float acc = 0.f;
            for (int d = 0; d < 16; ++d) acc += Wk[e * EMB + h * 16 + d] * qs[h * 16 + d];
            acc *= 0.25f;
            as_[i] = acc; ws[WS_A + i] = acc;
        }
        __syncthreads();
        if (t < 32) {
            int i = t >> 3, h = t & 7;
            const float* src = (i == 0) ? iw : (i == 1) ? iw + EMB : (i == 2) ? iw + 2 * EMB : ib;
            float acc = 0.f;
            for (int e = 0; e < EMB; ++e) acc += src[e] * as_[h * EMB + e];
            ws[WS_AC + t] = acc;
        }
    } else {
        int base = (b - 1) * 256 + t;
        const float kneg = -0.14619587891040738f;  // -ln(10000)/63
        if (base < LL * EMB) {
            int l = base >> 7, c = base & 127, ic = c & 63;
            float inv = expf((float)ic * kneg);
            float v = (float)l * inv;
            float r = (c < 64) ? sinf(v) : cosf(v);
            ws[WS_PE + base] = r;
            ((_Float16*)(ws + WS_PEH))[base] = (_Float16)r;
        } else if (base < LL * EMB + 512) {
            int j = base - LL * EMB;
            int iv = j >> 7, hd = j & 127;
            const float* src = (iv == 0) ? iw : (iv == 1) ? iw + EMB : (iv == 2) ? iw + 2 * EMB : ib;
            float acc = 0.f;
            for (int e = 0; e < EMB; ++e) acc += src[e] * Wv[e * EMB + hd];
            ws[WS_WVI + j] = acc;
        }
    }
}

// ---- S2a: PVH f16 [128][104] (pad zero) + PEA f32 [8][101]
__global__ void setup2a(const float* __restrict__ Wv, float* __restrict__ ws) {
    int idx = blockIdx.x * 256 + threadIdx.x;
    if (idx < 128 * 104) {
        int hd = idx / 104, l = idx - hd * 104;
        float acc = 0.f;
        if (l < LL) {
            const float* pr = ws + WS_PE + l * EMB;
            for (int e = 0; e < EMB; ++e) acc += pr[e] * Wv[e * EMB + hd];
        }
        ((_Float16*)(ws + WS_PVH))[idx] = (_Float16)acc;
    } else if (idx < 128 * 104 + Hh * LL) {
        int j = idx - 128 * 104;
        int h = j / LL, l = j - h * LL;
        const float* pr = ws + WS_PE + l * EMB;
        const float* ar = ws + WS_A + h * EMB;
        float acc = 0.f;
        for (int e = 0; e < EMB; ++e) acc += pr[e] * ar[e];
        ws[WS_PEA + j] = acc;
    }
}

// ---- S2b: WcwT f16 [128][128]
__global__ void setup2b(const float* __restrict__ Wcw, float* __restrict__ ws) {
    int idx = blockIdx.x * 256 + threadIdx.x;
    if (idx < 128 * 128) {
        int e = idx >> 7, hd = idx & 127;
        ((_Float16*)(ws + WS_WCT))[idx] = (_Float16)Wcw[hd * EMB + e];
    }
}

__global__ __launch_bounds__(TPB, 5) void main_kernel(
    const float* __restrict__ dist,
    const float* __restrict__ xy,
    const float* __restrict__ ndem,
    const float* __restrict__ ninf,
    const float* __restrict__ iw,
    const float* __restrict__ ib,
    const float* __restrict__ Wcb,
    const float* __restrict__ ws,
    float* __restrict__ out) {

    __shared__ __align__(16) char smem[PPB][AR_SIZE];
    const int tid  = threadIdx.x;
    const int w    = tid >> 6;
    const int lane = tid & 63;
    const int bw   = blockIdx.x * PPB + w;     // 2400 * 2 = 4800 exact

    char* A = smem[w];
    int*                hist4 = (int*)A;                      // [4][260]
    _Float16*           attnh = (_Float16*)A;                 // [8][112]
    _Float16*           uhh   = (_Float16*)(A + 1792);        // [128]
    float*              row   = (float*)A;                    // [1000]
    unsigned long long* list  = (unsigned long long*)(A + 4288);
    int*                sel   = (int*)(A + 5088);             // [101]
    unsigned char*      perm  = (unsigned char*)(A + 5492);   // [100] list-pos -> rank
    float*              smk   = (float*)(A + 5592);           // [101]
    float*              feat3 = (float*)(A + 5996);           // [303]
    _Float16*           mhh   = (_Float16*)(A + 7216);        // [128]
    float*              coef  = (float*)(A + 7472);           // [8][3]
    float*              coefM = (float*)(A + 7568);           // [4]

    const float* distRow = dist + (size_t)bw * Nn;
    const float* maskRow = ninf + (size_t)bw * Nn;
    const float* xyRow   = xy   + (size_t)bw * Nn * 2;
    const float* demRow  = ndem + (size_t)bw * Nn;

    // ---- phase 0: stream dist+mask (coalesced float4), keep mask in regs
    float dvf[16], mkf[16];
    {
        float4 dv[4], mv[4];
        #pragma unroll
        for (int c = 0; c < 4; ++c) {
            int n0 = c * 256 + lane * 4;
            if (n0 < Nn) {
                dv[c] = *(const float4*)(distRow + n0);
                mv[c] = *(const float4*)(maskRow + n0);
            } else {
                dv[c] = make_float4(0.f, 0.f, 0.f, 0.f);
                mv[c] = make_float4(0.f, 0.f, 0.f, 0.f);
            }
        }
        // zero sub-histograms while loads are in flight
        #pragma unroll
        for (int k = 0; k < 5; ++k) {
            int idx = lane + 64 * k;
            if (idx < 260) ((int4*)hist4)[idx] = make_int4(0, 0, 0, 0);
        }
        #pragma unroll
        for (int c = 0; c < 4; ++c) {
            dvf[4*c+0] = dv[c].x; dvf[4*c+1] = dv[c].y; dvf[4*c+2] = dv[c].z; dvf[4*c+3] = dv[c].w;
            mkf[4*c+0] = mv[c].x; mkf[4*c+1] = mv[c].y; mkf[4*c+2] = mv[c].z; mkf[4*c+3] = mv[c].w;
        }
    }
    // keys: node n = c*256 + lane*4 + j  (depot n==0 and pad n>=1000 excluded)
    unsigned long long rk[16];
    #pragma unroll
    for (int r = 0; r < 16; ++r) {
        int n = (r >> 2) * 256 + lane * 4 + (r & 3);
        unsigned long long kv = ~0ull;
        if (n >= 1 && n < Nn) {
            float de = dvf[r] - mkf[r];
            kv = ((unsigned long long)f2key(de) << 32) | (unsigned)n;
        }
        rk[r] = kv;
    }
    WSYNC();

    // ---- radix select (MSB-first, 4 bank-staggered sub-hists), wave-local
    unsigned long long prefix = 0;
    int shift = 56;
    int remRank = 99;
    const unsigned long long ltm = (1ull << lane) - 1ull;
    const int g0 = (lane >> 4) * 260;
    for (int round = 0; round < 8; ++round) {
        shift = 56 - 8 * round;
        #pragma unroll
        for (int r = 0; r < 16; ++r) {
            unsigned long long kv = rk[r];
            bool in = (kv != ~0ull) &&
                      (round == 0 || (kv >> (shift + 8)) == (prefix >> (shift + 8)));
            if (in) atomicAdd(&hist4[g0 + (int)((kv >> shift) & 0xffull)], 1);
        }
        WSYNC();
        int4 h0 = *(int4*)&hist4[0 * 260 + 4 * lane];
        int4 h1 = *(int4*)&hist4[1 * 260 + 4 * lane];
        int4 h2 = *(int4*)&hist4[2 * 260 + 4 * lane];
        int4 h3 = *(int4*)&hist4[3 * 260 + 4 * lane];
        int4 z = make_int4(0, 0, 0, 0);
        *(int4*)&hist4[0 * 260 + 4 * lane] = z;
        *(int4*)&hist4[1 * 260 + 4 * lane] = z;
        *(int4*)&hist4[2 * 260 + 4 * lane] = z;
        *(int4*)&hist4[3 * 260 + 4 * lane] = z;
        int cx = h0.x + h1.x + h2.x + h3.x;
        int cy = h0.y + h1.y + h2.y + h3.y;
        int cz = h0.z + h1.z + h2.z + h3.z;
        int cw = h0.w + h1.w + h2.w + h3.w;
        int s = cx + cy + cz + cw;
        int incl = s;
        #pragma unroll
        for (int o = 1; o < 64; o <<= 1) { int t = __shfl_up(incl, o, 64); if (lane >= o) incl += t; }
        int e0 = incl - s;
        int e1 = e0 + cx, e2 = e1 + cy, e3 = e2 + cz;
        int bc = -1, ec = 0, cc = 0;
        if (cx > 0 && remRank >= e0 && remRank < e1)      { bc = 4*lane+0; ec = e0; cc = cx; }
        if (cy > 0 && remRank >= e1 && remRank < e2)      { bc = 4*lane+1; ec = e1; cc = cy; }
        if (cz > 0 && remRank >= e2 && remRank < e3)      { bc = 4*lane+2; ec = e2; cc = cz; }
        if (cw > 0 && remRank >= e3 && remRank < e3 + cw) { bc = 4*lane+3; ec = e3; cc = cw; }
        unsigned long long fm = __ballot(bc >= 0);
        int srcl = __ffsll((unsigned long long)fm) - 1;
        bc = __shfl(bc, srcl, 64); ec = __shfl(ec, srcl, 64); cc = __shfl(cc, srcl, 64);
        prefix |= ((unsigned long long)(unsigned)bc) << shift;
        remRank -= ec;
        if (cc == 1) break;
    }
    // pivot key (unique match on resolved prefix)
    unsigned long long pk = 0; bool pf = false;
    #pragma unroll
    for (int r = 0; r < 16; ++r)
        if ((rk[r] >> shift) == (prefix >> shift)) { pk = rk[r]; pf = true; }
    {
        unsigned long long fm = __ballot(pf);
        int srcl = __ffsll((unsigned long long)fm) - 1;
        pk = __shfl(pk, srcl, 64);
    }
    const unsigned long long pivot = pk;

    // ---- ballot-compact the 100 keys <= pivot into list (p-order)
    int cnt_run = 0;
    #pragma unroll
    for (int r = 0; r < 16; ++r) {
        bool p = rk[r] <= pivot;
        unsigned long long m = __ballot(p);
        if (p) list[cnt_run + (int)__popcll(m & ltm)] = rk[r];
        cnt_run += (int)__popcll(m);
    }
    WSYNC();

    // ---- parallel rank: perm[p] = rank+1 ; norm max
    {
        unsigned long long kv0 = list[lane];
        const bool has1 = lane < (LOCALK - 64);
        unsigned long long kv1 = has1 ? list[lane + 64] : ~0ull;
        int r0 = 0, r1 = 0;
        #pragma unroll 4
        for (int j = 0; j < LOCALK; ++j) {
            unsigned long long lv = list[j];
            r0 += (lv < kv0);
            r1 += (lv < kv1);
        }
        float v0 = key2f((unsigned)(kv0 >> 32));
        float dvm = isinf(v0) ? 0.f : v0;
        perm[lane] = (unsigned char)(r0 + 1);
        if (has1) {
            float v1 = key2f((unsigned)(kv1 >> 32));
            perm[lane + 64] = (unsigned char)(r1 + 1);
            dvm = fmaxf(dvm, isinf(v1) ? 0.f : v1);
        }
        #pragma unroll
        for (int o = 32; o > 0; o >>= 1) dvm = fmaxf(dvm, __shfl_xor(dvm, o, 64));
        const float nmax = dvm;
        const bool  norm_on = (nmax != 0.f);
        const float nfac = nmax + 1e-6f;
        WSYNC();

        // ---- streamed feature scatter: re-derive p per key, write at rank (NO global gather)
        int crun = 0;
        #pragma unroll
        for (int half = 0; half < 2; ++half) {
            // stream xy + ndem for this half's 8 nodes (coalesced float4)
            float xs[8], ys[8], dd[8];
            #pragma unroll
            for (int cl = 0; cl < 2; ++cl) {
                int c = half * 2 + cl;
                int n0 = c * 256 + lane * 4;
                float4 a0, a1, d0;
                if (n0 < Nn) {
                    a0 = *(const float4*)(xyRow + 2 * n0);
                    a1 = *(const float4*)(xyRow + 2 * n0 + 4);
                    d0 = *(const float4*)(demRow + n0);
                } else {
                    a0 = a1 = d0 = make_float4(0.f, 0.f, 0.f, 0.f);
                }
                xs[4*cl+0] = a0.x; ys[4*cl+0] = a0.y;
                xs[4*cl+1] = a0.z; ys[4*cl+1] = a0.w;
                xs[4*cl+2] = a1.x; ys[4*cl+2] = a1.y;
                xs[4*cl+3] = a1.z; ys[4*cl+3] = a1.w;
                dd[4*cl+0] = d0.x; dd[4*cl+1] = d0.y; dd[4*cl+2] = d0.z; dd[4*cl+3] = d0.w;
            }
            #pragma unroll
            for (int q = 0; q < 8; ++q) {
                int r = half * 8 + q;
                unsigned long long kv = rk[r];
                bool p = kv <= pivot;
                unsigned long long m = __ballot(p);
                int pos = crun + (int)__popcll(m & ltm);
                crun += (int)__popcll(m);
                if (p) {
                    int rnk = perm[pos];
                    float val = key2f((unsigned)(kv >> 32));
                    bool infm = isinf(val);
                    float fx = infm ? 0.f : xs[q];
                    float fy = infm ? 0.f : ys[q];
                    float fd = infm ? 0.f : dd[q];
                    if (norm_on) { fx /= nfac; fy /= nfac; }
                    int n = (int)(kv & 0xffffffu);
                    feat3[rnk] = fx; feat3[101 + rnk] = fy; feat3[202 + rnk] = fd;
                    smk[rnk] = mkf[r];
                    sel[rnk] = n | (infm ? 0x40000000 : 0);
                }
            }
        }
        if (lane == 0) {   // depot: rank 0, node 0, inf flag
            feat3[0] = 0.f; feat3[101] = 0.f; feat3[202] = 0.f;
            smk[0] = mkf[0];
            sel[0] = 0x40000000;
        }
    }
    WSYNC();

    // ---- fused scores + softmax + coef: 8 lanes per head
    const int h = lane >> 3, ln8 = lane & 7;
    {
        const float A0 = ws[WS_AC + h], A1 = ws[WS_AC + 8 + h];
        const float A2 = ws[WS_AC + 16 + h], Cc = ws[WS_AC + 24 + h];
        const float* pea = ws + WS_PEA + h * LL;
        float ev[14];
        float mx = -INFINITY;
        #pragma unroll
        for (int k = 0; k < 14; ++k) {
            int l = ln8 + 8 * k;
            float sv = -INFINITY;
            if (l < LL)
                sv = feat3[l] * A0 + feat3[101 + l] * A1 + feat3[202 + l] * A2
                   + Cc + pea[l] + smk[l];
            ev[k] = sv;
            mx = fmaxf(mx, sv);
        }
        #pragma unroll
        for (int o = 1; o < 8; o <<= 1) mx = fmaxf(mx, __shfl_xor(mx, o, 64));
        float sm = 0.f;
        #pragma unroll
        for (int k = 0; k < 14; ++k) {
            int l = ln8 + 8 * k;
            float e = (l < LL) ? __expf(ev[k] - mx) : 0.f;
            ev[k] = e; sm += e;
        }
        #pragma unroll
        for (int o = 1; o < 8; o <<= 1) sm += __shfl_xor(sm, o, 64);
        const float ainv = 1.f / sm;
        #pragma unroll
        for (int k = 0; k < 14; ++k) {
            int l = ln8 + 8 * k;                 // l <= 111 always
            attnh[h * 112 + l] = (_Float16)(ev[k] * ainv);
        }
        float c0 = 0.f, c1 = 0.f, c2 = 0.f;
        #pragma unroll
        for (int k = 0; k < 13; ++k) {
            int l = ln8 + 8 * k;
            if (l < LL) {
                float at = ev[k] * ainv;
                c0 += at * feat3[l]; c1 += at * feat3[101 + l]; c2 += at * feat3[202 + l];
            }
        }
        #pragma unroll
        for (int o = 1; o < 8; o <<= 1) {
            c0 += __shfl_xor(c0, o, 64); c1 += __shfl_xor(c1, o, 64); c2 += __shfl_xor(c2, o, 64);
        }
        if (ln8 == 0) { coef[h * 3 + 0] = c0; coef[h * 3 + 1] = c1; coef[h * 3 + 2] = c2; }
    }
    WSYNC();

    // ---- u[hd] = attn[h] . PV[hd] + rank-3 corrections
    #pragma unroll
    for (int t = 0; t < 2; ++t) {
        int hd = lane + 64 * t;
        int hh = hd >> 4;
        const half8v* pv = (const half8v*)((const _Float16*)(ws + WS_PVH) + hd * 104);
        const half8v* at = (const half8v*)(attnh + hh * 112);
        float d0 = 0.f, d1 = 0.f, d2 = 0.f, d3 = 0.f;
        #pragma unroll
        for (int j = 0; j < 13; ++j) dot8(d0, d1, d2, d3, pv[j], at[j]);
        float u = (d0 + d1) + (d2 + d3)
                + coef[hh * 3 + 0] * ws[WS_WVI + hd]
                + coef[hh * 3 + 1] * ws[WS_WVI + 128 + hd]
                + coef[hh * 3 + 2] * ws[WS_WVI + 256 + hd]
                + ws[WS_WVI + 384 + hd];
        uhh[hd] = (_Float16)u;
    }
    WSYNC();

    // ---- mh[e] = Wcb[e] + u . WcwT[e]
    #pragma unroll
    for (int t = 0; t < 2; ++t) {
        int e = lane + 64 * t;
        const half8v* wr = (const half8v*)((const _Float16*)(ws + WS_WCT) + e * 128);
        const half8v* ur = (const half8v*)uhh;
        float d0 = 0.f, d1 = 0.f, d2 = 0.f, d3 = 0.f;
        #pragma unroll
        for (int j = 0; j < 16; ++j) dot8(d0, d1, d2, d3, wr[j], ur[j]);
        mhh[e] = (_Float16)(Wcb[e] + (d0 + d1) + (d2 + d3));
    }
    WSYNC();

    // ---- coefM[g] = mh . {w0,w1,w2,b}   (16 lanes per g)
    {
        int g = lane & 3;
        const float* src = (g == 0) ? iw : (g == 1) ? iw + EMB : (g == 2) ? iw + 2 * EMB : ib;
        float v = 0.f;
        #pragma unroll
        for (int j = 0; j < 8; ++j) {
            int e = (lane >> 2) + 16 * j;
            v += (float)mhh[e] * src[e];
        }
        v += __shfl_xor(v, 4, 64); v += __shfl_xor(v, 8, 64);
        v += __shfl_xor(v, 16, 64); v += __shfl_xor(v, 32, 64);
        if (lane < 4) coefM[lane] = v;
    }
    // zero LDS row (attnh/uhh/hist/list all dead now)
    {
        float4 z = make_float4(0.f, 0.f, 0.f, 0.f);
        ((float4*)row)[lane] = z;
        ((float4*)row)[lane + 64] = z;
        ((float4*)row)[lane + 128] = z;
        if (lane < 58) ((float4*)row)[lane + 192] = z;
    }
    WSYNC();

    // ---- score2[l] = (base + mh.pe[l]) / sqrt(128); scatter into LDS row
    auto score2 = [&](int t) {
        float base = feat3[t] * coefM[0] + feat3[101 + t] * coefM[1]
                   + feat3[202 + t] * coefM[2] + coefM[3];
        const half8v* pr = (const half8v*)((const _Float16*)(ws + WS_PEH) + t * 128);
        const half8v* mr = (const half8v*)mhh;
        float d0 = 0.f, d1 = 0.f, d2 = 0.f, d3 = 0.f;
        #pragma unroll
        for (int j = 0; j < 16; ++j) dot8(d0, d1, d2, d3, pr[j], mr[j]);
        row[sel[t] & 0xffffff] = (base + (d0 + d1) + (d2 + d3)) * 0.08838834764831845f;
    };
    score2(lane);
    if (lane < LL - 64) score2(lane + 64);
    WSYNC();

    // ---- stream the row out coalesced
    float* outRow = out + (size_t)bw * Nn;
    ((float4*)outRow)[lane]       = ((float4*)row)[lane];
    ((float4*)outRow)[lane + 64]  = ((float4*)row)[lane + 64];
    ((float4*)outRow)[lane + 128] = ((float4*)row)[lane + 128];
    if (lane < 58) ((float4*)outRow)[lane + 192] = ((float4*)row)[lane + 192];
}

extern "C" void kernel_launch(void* const* d_in, const int* in_sizes, int n_in,
                              void* d_out, int out_size, void* d_ws, size_t ws_size,
                              hipStream_t stream) {
    // 0 theta, 1 dist, 2 xy, 3 norm_demand, 4 ninf_mask,
    // 5 init_w, 6 init_b, 7 cur_token, 8 Wq, 9 Wk, 10 Wv, 11 Wc_w, 12 Wc_b
    const float* dist  = (const float*)d_in[1];
    const float* xy    = (const float*)d_in[2];
    const float* ndem  = (const float*)d_in[3];
    const float* ninf  = (const float*)d_in[4];
    const float* initw = (const float*)d_in[5];
    const float* initb = (const float*)d_in[6];
    const float* cur   = (const float*)d_in[7];
    const float* Wq    = (const float*)d_in[8];
    const float* Wk    = (const float*)d_in[9];
    const float* Wv    = (const float*)d_in[10];
    const float* Wcw   = (const float*)d_in[11];
    const float* Wcb   = (const float*)d_in[12];
    float* out = (float*)d_out;
    float* ws  = (float*)d_ws;

    hipLaunchKernelGGL(setup1,  dim3(56), dim3(256), 0, stream, cur, Wq, Wk, initw, initb, Wv, ws);
    hipLaunchKernelGGL(setup2a, dim3(56), dim3(256), 0, stream, Wv, ws);
    hipLaunchKernelGGL(setup2b, dim3(64), dim3(256), 0, stream, Wcw, ws);
    hipLaunchKernelGGL(main_kernel, dim3(Bb * Ww / PPB), dim3(TPB), 0, stream,
                       dist, xy, ndem, ninf, initw, initb, Wcb, ws, out);
}